// Round 4
// baseline (943.688 us; speedup 1.0000x reference)
//
#include <hip/hip_runtime.h>
#include <hip/hip_bf16.h>
#include <math.h>

#define SLOPE 0.01f
#define EPS_LN 1e-5f

typedef __hip_bfloat16 bf16;
typedef __attribute__((ext_vector_type(8))) short short8;
typedef __attribute__((ext_vector_type(4))) float f32x4;

__device__ __forceinline__ float leakyf(float x) { return x < 0.f ? SLOPE * x : x; }

__device__ __forceinline__ float b2f(short s) {
    unsigned u = ((unsigned)(unsigned short)s) << 16;
    return __builtin_bit_cast(float, u);
}
__device__ __forceinline__ short f2b(float f) {
    __hip_bfloat16 h = __float2bfloat16(f);
    return *(short*)&h;
}

__device__ __forceinline__ void gload_lds16(const void* g, void* l) {
    __builtin_amdgcn_global_load_lds(
        (const __attribute__((address_space(1))) void*)g,
        (__attribute__((address_space(3))) void*)l, 16, 0, 0);
}

// ===========================================================================
// 8-phase 256x256 GEMM (T2+T3+T4+T5), 512 thr = 8 waves (2M x 4N), BK=64.
// LDS: 4 rotating K-half regions per operand (256 rows x 32 K each), 128 KiB.
// region(tile s, khalf kh) = (2s+kh) & 3.
// Race ledger (identical to round-3 verified version):
//   stage schedule per tile s: ph1 A(s+1,k1), ph2 B(s+1,k1), ph3 A(s+2,k0),
//   ph4 B(s+2,k0). vmcnt(8) at end of ph2 gates (s,k1) reads at ph3;
//   vmcnt(8) at end of ph4 gates (s+1,k0) reads at next-tile ph1.
// Round-4 changes (schedule quality only, ledger unchanged):
//   - even ds_read split: ph(kh,first): 4 A-frags + 4 B-frags (B held in regs),
//     ph(kh,second): 4 A-frags. 8/4/8/4 per K-tile instead of 10/2/10/2.
//   - no explicit lgkmcnt(0)/sched_barrier: LDS reads are compiler-visible,
//     hipcc emits fine-grained lgkmcnt before each consuming MFMA. Memory ops
//     cannot cross the asm "memory" barriers; acc dep chains bound MFMA drift.
// LDS swizzle: phys 16B-chunk P = L ^ ((L>>3)&7), L = row*4 + kg. Involution;
//   staging pre-swizzles the GLOBAL source, LDS dest linear; reads same XOR.
// MODE 0 (r1): K=1920, ldA=640,  MT=64,  NT=10 (N-merge: branch = bx>=5)
// MODE 1 (r2): K=3840, ldA=1280, MT=128, NT=5  (M-merge: branch = mt>=64)
// ===========================================================================
#define MM(ai, bi, mm, qq)                                                     \
    acc[mm][qq] = __builtin_amdgcn_mfma_f32_16x16x32_bf16(ai, bi, acc[mm][qq], 0, 0, 0)
#define MFMA16(MB)                                                             \
    MM(a0, bq0, MB + 0, 0); MM(a1, bq0, MB + 1, 0); MM(a2, bq0, MB + 2, 0);    \
    MM(a3, bq0, MB + 3, 0);                                                    \
    MM(a0, bq1, MB + 0, 1); MM(a1, bq1, MB + 1, 1); MM(a2, bq1, MB + 2, 1);    \
    MM(a3, bq1, MB + 3, 1);                                                    \
    MM(a0, bq2, MB + 0, 2); MM(a1, bq2, MB + 1, 2); MM(a2, bq2, MB + 2, 2);    \
    MM(a3, bq2, MB + 3, 2);                                                    \
    MM(a0, bq3, MB + 0, 3); MM(a1, bq3, MB + 1, 3); MM(a2, bq3, MB + 2, 3);    \
    MM(a3, bq3, MB + 3, 3);
#define BARRIER asm volatile("s_barrier" ::: "memory")

template <int MODE>
__global__ __launch_bounds__(512, 1) void gemm8_bf16(
    const bf16* __restrict__ A0, const bf16* __restrict__ A1,
    const bf16* __restrict__ Bt0, const bf16* __restrict__ Bt1,
    const float* __restrict__ bias0, const float* __restrict__ bias1,
    bf16* __restrict__ Y0, bf16* __restrict__ Y1,
    float2* __restrict__ sacc)
{
    constexpr int K   = (MODE == 0) ? 1920 : 3840;
    constexpr int LDA = (MODE == 0) ? 640 : 1280;
    constexpr int MT  = (MODE == 0) ? 64 : 128;
    constexpr int NKT = K / 64;

    __shared__ bf16 Ash[4][256][32];
    __shared__ bf16 Bsh[4][256][32];

    const int nwg = gridDim.x;
    const int wid = (blockIdx.x & 7) * (nwg >> 3) + (blockIdx.x >> 3);
    const int mt = wid % MT;       // mt-inner: B-panel stays L2-resident
    const int bxg = wid / MT;
    int branch, bxl, mtl;
    if (MODE == 0) { branch = bxg >= 5; bxl = bxg - branch * 5; mtl = mt; }
    else           { branch = mt >= 64; bxl = bxg; mtl = mt & 63; }
    const int batch = mtl >> 2;
    const int mrow0 = (mtl & 3) * 256;
    const bf16* Apad = branch ? A1 : A0;
    const bf16* Bt   = branch ? Bt1 : Bt0;
    const float* bias = branch ? bias1 : bias0;
    bf16* Yb = branch ? Y1 : Y0;
    const bf16* Abase = Apad + ((long)batch * 1026 + mrow0) * LDA;
    const bf16* Bbase = Bt + (long)bxl * 256 * K;

    const int tid = threadIdx.x;
    const int wave = tid >> 6, lane = tid & 63;
    const int wm = wave >> 2, wn = wave & 3;
    const int r16 = lane & 15, g4 = lane >> 4;

    auto stageA = [&](int s, int kh) {
        char* lb = (char*)&Ash[(2 * s + kh) & 3][0][0];
#pragma unroll
        for (int j = 0; j < 2; ++j) {
            int c = j * 512 + tid;
            int L = c ^ ((c >> 3) & 7);
            int row = L >> 2, kg = L & 3;
            gload_lds16(Abase + (long)row * LDA + (s * 64 + kh * 32 + kg * 8),
                        lb + c * 16);
        }
    };
    auto stageB = [&](int s, int kh) {
        char* lb = (char*)&Bsh[(2 * s + kh) & 3][0][0];
#pragma unroll
        for (int j = 0; j < 2; ++j) {
            int c = j * 512 + tid;
            int L = c ^ ((c >> 3) & 7);
            int row = L >> 2, kg = L & 3;
            gload_lds16(Bbase + (long)row * K + (s * 64 + kh * 32 + kg * 8),
                        lb + c * 16);
        }
    };
    auto ldA8 = [&](int reg, int mi) -> short8 {
        int row = wm * 128 + mi * 16 + r16;
        int P = ((row << 2) | g4) ^ ((row >> 1) & 7);
        return *(const short8*)((const char*)&Ash[reg][0][0] + P * 16);
    };
    auto ldB8 = [&](int reg, int q) -> short8 {
        int row = wn * 64 + q * 16 + r16;
        int P = ((row << 2) | g4) ^ ((row >> 1) & 7);
        return *(const short8*)((const char*)&Bsh[reg][0][0] + P * 16);
    };

    f32x4 acc[8][4];
#pragma unroll
    for (int i = 0; i < 8; ++i)
#pragma unroll
        for (int j = 0; j < 4; ++j) acc[i][j] = (f32x4){0.f, 0.f, 0.f, 0.f};

    // prologue: events (0,A,k0)(0,B,k0)(0,A,k1)(0,B,k1)(1,A,k0)(1,B,k0)
    stageA(0, 0); stageB(0, 0);
    stageA(0, 1); stageB(0, 1);
    stageA(1, 0); stageB(1, 0);
    asm volatile("s_waitcnt vmcnt(8)" ::: "memory");  // (0,k0) landed
    BARRIER;

    for (int s = 0; s < NKT; ++s) {
        const int rA = (2 * s) & 3;
        const int rB = (2 * s + 1) & 3;
        short8 a0, a1, a2, a3, bq0, bq1, bq2, bq3;
        // phase 1: kh=0, mi 0-3 (+ all B for kh=0)
        a0 = ldA8(rA, 0); bq0 = ldB8(rA, 0);
        a1 = ldA8(rA, 1); bq1 = ldB8(rA, 1);
        a2 = ldA8(rA, 2); bq2 = ldB8(rA, 2);
        a3 = ldA8(rA, 3); bq3 = ldB8(rA, 3);
        if (s + 1 < NKT) stageA(s + 1, 1);
        BARRIER;
        __builtin_amdgcn_s_setprio(1);
        MFMA16(0)
        __builtin_amdgcn_s_setprio(0);
        BARRIER;
        // phase 2: kh=0, mi 4-7 (B held in regs)
        a0 = ldA8(rA, 4); a1 = ldA8(rA, 5); a2 = ldA8(rA, 6); a3 = ldA8(rA, 7);
        if (s + 1 < NKT) stageB(s + 1, 1);
        BARRIER;
        __builtin_amdgcn_s_setprio(1);
        MFMA16(4)
        __builtin_amdgcn_s_setprio(0);
        asm volatile("s_waitcnt vmcnt(8)" ::: "memory");  // gate (s,k1)
        BARRIER;
        // phase 3: kh=1, mi 0-3
        a0 = ldA8(rB, 0); bq0 = ldB8(rB, 0);
        a1 = ldA8(rB, 1); bq1 = ldB8(rB, 1);
        a2 = ldA8(rB, 2); bq2 = ldB8(rB, 2);
        a3 = ldA8(rB, 3); bq3 = ldB8(rB, 3);
        if (s + 2 < NKT) stageA(s + 2, 0);
        BARRIER;
        __builtin_amdgcn_s_setprio(1);
        MFMA16(0)
        __builtin_amdgcn_s_setprio(0);
        BARRIER;
        // phase 4: kh=1, mi 4-7
        a0 = ldA8(rB, 4); a1 = ldA8(rB, 5); a2 = ldA8(rB, 6); a3 = ldA8(rB, 7);
        if (s + 2 < NKT) stageB(s + 2, 0);
        BARRIER;
        __builtin_amdgcn_s_setprio(1);
        MFMA16(4)
        __builtin_amdgcn_s_setprio(0);
        asm volatile("s_waitcnt vmcnt(8)" ::: "memory");  // gate (s+1,k0)
        BARRIER;
    }
    asm volatile("s_waitcnt vmcnt(0) lgkmcnt(0)" ::: "memory");

    float ssum = 0.f, sq = 0.f;
#pragma unroll
    for (int mi = 0; mi < 8; ++mi) {
#pragma unroll
        for (int q = 0; q < 4; ++q) {
            int col = bxl * 256 + wn * 64 + q * 16 + r16;
            float bv = bias[col];
#pragma unroll
            for (int rr = 0; rr < 4; ++rr) {
                int row = mrow0 + wm * 128 + mi * 16 + g4 * 4 + rr;
                float v = acc[mi][q][rr] + bv;
                Yb[((long)batch * 1024 + row) * 1280 + col] = __float2bfloat16(v);
                ssum += v; sq += v * v;
            }
        }
    }
    __syncthreads();
    float* red = (float*)&Ash[0][0][0];
    red[tid] = ssum; red[512 + tid] = sq;
    __syncthreads();
    for (int o = 256; o; o >>= 1) {
        if (tid < o) { red[tid] += red[tid + o]; red[512 + tid] += red[512 + tid + o]; }
        __syncthreads();
    }
    if (tid == 0) {
        atomicAdd(&sacc[branch * 16 + batch].x, red[0]);
        atomicAdd(&sacc[branch * 16 + batch].y, red[512]);
    }
}

// ---------------------------------------------------------------------------
// 128x128 2-phase GEMM (round-2 proven) — used for cv3 and MLP.
// ---------------------------------------------------------------------------
template <int EPI>
__global__ __launch_bounds__(256, 2) void gemm_bf16(
    const bf16* __restrict__ A, long sA, int ldA,
    const bf16* __restrict__ Bt,
    const float* __restrict__ bias,
    void* __restrict__ Outv, long sO, int ldO, int K,
    int gx, int gy, float2* __restrict__ stats)
{
    __shared__ bf16 As[128][64];
    __shared__ bf16 Bs[128][64];

    const int nwg = gridDim.x;
    const int wid = (blockIdx.x & 7) * (nwg >> 3) + (blockIdx.x >> 3);
    const int bx = wid % gx;
    const int by = (wid / gx) % gy;
    const int bz = wid / (gx * gy);

    const bf16* Ab = A + (long)bz * sA + (long)by * 128 * ldA;
    const bf16* Bb = Bt + (long)bx * 128 * K;
    const int tid = threadIdx.x;
    const int wave = tid >> 6, lane = tid & 63;
    const int moff = (wave >> 1) * 64, noff = (wave & 1) * 64;
    const int r16 = lane & 15, g4 = lane >> 4;
    const int r7 = r16 & 7;

    f32x4 acc[4][4];
#pragma unroll
    for (int i = 0; i < 4; ++i)
#pragma unroll
        for (int j = 0; j < 4; ++j)
            acc[i][j] = (f32x4){0.f, 0.f, 0.f, 0.f};

    for (int k0 = 0; k0 < K; k0 += 64) {
        __syncthreads();
#pragma unroll
        for (int i = 0; i < 4; ++i) {
            int chunk = i * 256 + tid;
            int row = chunk >> 3;
            int kc = (chunk ^ (chunk >> 3)) & 7;
            gload_lds16(Ab + (long)row * ldA + (k0 + kc * 8),
                        (char*)(&As[0][0]) + (i * 256 + wave * 64) * 16);
        }
#pragma unroll
        for (int i = 0; i < 4; ++i) {
            int chunk = i * 256 + tid;
            int row = chunk >> 3;
            int kc = (chunk ^ (chunk >> 3)) & 7;
            gload_lds16(Bb + (long)row * K + (k0 + kc * 8),
                        (char*)(&Bs[0][0]) + (i * 256 + wave * 64) * 16);
        }
        __syncthreads();
#pragma unroll
        for (int kk = 0; kk < 2; ++kk) {
            short8 af[4], bfr[4];
#pragma unroll
            for (int mi = 0; mi < 4; ++mi)
                af[mi] = *(const short8*)&As[moff + mi * 16 + r16][((kk * 4 + g4) ^ r7) * 8];
#pragma unroll
            for (int ni = 0; ni < 4; ++ni)
                bfr[ni] = *(const short8*)&Bs[noff + ni * 16 + r16][((kk * 4 + g4) ^ r7) * 8];
#pragma unroll
            for (int mi = 0; mi < 4; ++mi)
#pragma unroll
                for (int ni = 0; ni < 4; ++ni)
                    acc[mi][ni] = __builtin_amdgcn_mfma_f32_16x16x32_bf16(
                        af[mi], bfr[ni], acc[mi][ni], 0, 0, 0);
        }
    }

    float s = 0.f, q = 0.f;
#pragma unroll
    for (int mi = 0; mi < 4; ++mi) {
#pragma unroll
        for (int ni = 0; ni < 4; ++ni) {
            int col = bx * 128 + noff + ni * 16 + r16;
            float bv = bias[col];
#pragma unroll
            for (int r = 0; r < 4; ++r) {
                int row = by * 128 + moff + mi * 16 + g4 * 4 + r;
                float v = acc[mi][ni][r] + bv;
                if (EPI == 1) {
                    ((float*)Outv)[(long)bz * sO + (long)row * ldO + col] = leakyf(v);
                } else {
                    ((bf16*)Outv)[(long)bz * sO + (long)row * ldO + col] = __float2bfloat16(v);
                    s += v; q += v * v;
                }
            }
        }
    }
    if (EPI == 0) {
        __syncthreads();
        float* red = (float*)&As[0][0];
        float* red2 = red + 256;
        red[tid] = s; red2[tid] = q;
        __syncthreads();
        for (int o = 128; o; o >>= 1) {
            if (tid < o) { red[tid] += red[tid + o]; red2[tid] += red2[tid + o]; }
            __syncthreads();
        }
        if (tid == 0) {
            atomicAdd(&stats[bz].x, red[0]);
            atomicAdd(&stats[bz].y, red2[0]);
        }
    }
}

// ---------------------------------------------------------------------------
__global__ void zero_stats_k(float2* s) {
    if (threadIdx.x < 80) s[threadIdx.x] = make_float2(0.f, 0.f);
}

__global__ void fin_k(const float2* __restrict__ acc, float2* __restrict__ stat,
                      float invN, int n) {
    int b = threadIdx.x;
    if (b < n) {
        float m = acc[b].x * invN;
        float var = acc[b].y * invN - m * m;
        stat[b] = make_float2(m, rsqrtf(var + EPS_LN));
    }
}

// ---------------------------------------------------------------------------
__global__ void pack_feats_v_k(const float* __restrict__ f, bf16* __restrict__ xp, int C)
{
    long i8 = (long)blockIdx.x * 256 + threadIdx.x;
    long total8 = 16L * 1026 * C / 8;
    if (i8 >= total8) return;
    long e = i8 * 8;
    int c = (int)(e % C);
    long t = e / C;
    int r = (int)(t % 1026);
    int b = (int)(t / 1026);
    short8 o;
    if (r == 0 || r == 1025) {
#pragma unroll
        for (int j = 0; j < 8; ++j) o[j] = 0;
    } else {
        const float* src = f + ((long)b * 1024 + (r - 1)) * C + c;
        f32x4 v0 = *(const f32x4*)src;
        f32x4 v1 = *(const f32x4*)(src + 4);
#pragma unroll
        for (int j = 0; j < 4; ++j) { o[j] = f2b(v0[j]); o[j + 4] = f2b(v1[j]); }
    }
    *(short8*)(xp + e) = o;
}

__global__ void norm_pack_v_k(const bf16* __restrict__ y, const float2* __restrict__ stat,
                              bf16* __restrict__ xp, int C)
{
    long i8 = (long)blockIdx.x * 256 + threadIdx.x;
    long total8 = 16L * 1026 * C / 8;
    if (i8 >= total8) return;
    long e = i8 * 8;
    int c = (int)(e % C);
    long t = e / C;
    int r = (int)(t % 1026);
    int b = (int)(t / 1026);
    short8 o;
    if (r == 0 || r == 1025) {
#pragma unroll
        for (int j = 0; j < 8; ++j) o[j] = 0;
    } else {
        float2 st = stat[b];
        short8 v = *(const short8*)(y + ((long)b * 1024 + (r - 1)) * C + c);
#pragma unroll
        for (int j = 0; j < 8; ++j)
            o[j] = f2b(leakyf((b2f(v[j]) - st.x) * st.y));
    }
    *(short8*)(xp + e) = o;
}

__global__ void norm_addf_v_k(const bf16* __restrict__ y, const float2* __restrict__ stat,
                              const float* __restrict__ feats, bf16* __restrict__ acat)
{
    long i8 = (long)blockIdx.x * 256 + threadIdx.x;
    long total8 = 16L * 1024 * 640 / 8;
    if (i8 >= total8) return;
    long e = i8 * 8;
    int c = (int)(e % 640);
    int l = (int)((e / 640) % 1024);
    int b = (int)(e / (640L * 1024));
    float2 st = stat[b];
    short8 v = *(const short8*)(y + e);
    f32x4 f0 = *(const f32x4*)(feats + e);
    f32x4 f1 = *(const f32x4*)(feats + e + 4);
    short8 o;
#pragma unroll
    for (int j = 0; j < 4; ++j) {
        o[j] = f2b(leakyf((b2f(v[j]) - st.x) * st.y) + f0[j]);
        o[j + 4] = f2b(leakyf((b2f(v[j + 4]) - st.x) * st.y) + f1[j]);
    }
    *(short8*)(acat + ((long)b * 1024 + l) * 1280 + 640 + c) = o;
}

// ---------------------------------------------------------------------------
// cp conv3 (N=2): one wave per (b,l), short8-vectorized.
// ---------------------------------------------------------------------------
__global__ void conv3cp_k(const bf16* __restrict__ xp, const bf16* __restrict__ w3,
                          const float* __restrict__ b3, float* __restrict__ sw)
{
    int wid = (int)((blockIdx.x * 256 + threadIdx.x) >> 6);
    int lane = threadIdx.x & 63;
    int b = wid >> 10, l = wid & 1023;
    const short8* xr = (const short8*)(xp + ((long)b * 1026 + l) * 1280);
    const short8* w0 = (const short8*)w3;
    const short8* w1 = (const short8*)(w3 + 3840);
    float a0 = 0.f, a1 = 0.f;
    for (int c = lane; c < 480; c += 64) {
        short8 x = xr[c], u = w0[c], v = w1[c];
#pragma unroll
        for (int j = 0; j < 8; ++j) {
            float xf = b2f(x[j]);
            a0 += xf * b2f(u[j]);
            a1 += xf * b2f(v[j]);
        }
    }
    for (int o = 32; o; o >>= 1) { a0 += __shfl_down(a0, o); a1 += __shfl_down(a1, o); }
    if (lane == 0) {
        sw[b * 2048 + l] = a0 + b3[0];
        sw[b * 2048 + 1024 + l] = a1 + b3[1];
    }
}

// ---------------------------------------------------------------------------
__global__ __launch_bounds__(256) void cp_post_k(const float* __restrict__ sw,
                                                 float* __restrict__ stdb,
                                                 float* __restrict__ wb)
{
    int b = blockIdx.x, tid = threadIdx.x;
    __shared__ float s0[1024], s1[1024], red[256];
    const float* p = sw + b * 2048;
    float s = 0.f, q = 0.f;
    for (int l = tid; l < 1024; l += 256) {
        float v0 = p[l], v1 = p[1024 + l];
        s0[l] = v0; s1[l] = v1;
        s += v0 + v1; q += v0 * v0 + v1 * v1;
    }
    red[tid] = s; __syncthreads();
    for (int o = 128; o; o >>= 1) { if (tid < o) red[tid] += red[tid + o]; __syncthreads(); }
    float mean = red[0] / 2048.f; __syncthreads();
    red[tid] = q; __syncthreads();
    for (int o = 128; o; o >>= 1) { if (tid < o) red[tid] += red[tid + o]; __syncthreads(); }
    float inv = rsqrtf(red[0] / 2048.f - mean * mean + EPS_LN); __syncthreads();
    for (int l = tid; l < 1024; l += 256) {
        s0[l] = leakyf((s0[l] - mean) * inv);
        s1[l] = leakyf((s1[l] - mean) * inv);
    }
    __syncthreads();
    float mx = -1e30f;
    for (int l = tid; l < 1024; l += 256) mx = fmaxf(mx, s0[l]);
    red[tid] = mx; __syncthreads();
    for (int o = 128; o; o >>= 1) { if (tid < o) red[tid] = fmaxf(red[tid], red[tid + o]); __syncthreads(); }
    mx = red[0]; __syncthreads();
    float se = 0.f;
    for (int l = tid; l < 1024; l += 256) { float e = __expf(s0[l] - mx); s0[l] = e; se += e; }
    red[tid] = se; __syncthreads();
    for (int o = 128; o; o >>= 1) { if (tid < o) red[tid] += red[tid + o]; __syncthreads(); }
    float rs = 1.f / red[0]; __syncthreads();
    for (int l = tid; l < 1024; l += 256) stdb[b * 1024 + l] = 102.4f * s0[l] * rs;
    mx = -1e30f;
    for (int l = tid; l < 1024; l += 256) mx = fmaxf(mx, s1[l]);
    red[tid] = mx; __syncthreads();
    for (int o = 128; o; o >>= 1) { if (tid < o) red[tid] = fmaxf(red[tid], red[tid + o]); __syncthreads(); }
    mx = red[0]; __syncthreads();
    se = 0.f;
    for (int l = tid; l < 1024; l += 256) { float e = __expf(s1[l] - mx); s1[l] = e; se += e; }
    red[tid] = se; __syncthreads();
    for (int o = 128; o; o >>= 1) { if (tid < o) red[tid] += red[tid + o]; __syncthreads(); }
    rs = 1.f / red[0]; __syncthreads();
    for (int l = tid; l < 1024; l += 256) wb[b * 1024 + l] = s1[l] * rs;
}

// ---------------------------------------------------------------------------
__global__ __launch_bounds__(256) void pool_k(const float* __restrict__ feats,
                                              const float* __restrict__ stdb,
                                              const float* __restrict__ wb,
                                              bf16* __restrict__ acat)
{
    int i = blockIdx.x, b = blockIdx.y, tid = threadIdx.x;
    float sd = stdb[b * 1024 + i];
    float den = 1e-5f + 2.f * sd * sd;
    float inv = 1.f / den;
    int R = (int)sqrtf(11.5129255f * den) + 1;
    int jlo = max(0, i - R), jhi = min(1023, i + R);
    __shared__ float cj[256];
    float a0 = 0.f, a1 = 0.f, a2 = 0.f;
    const float* fb = feats + (long)b * 1024 * 640;
    for (int j0 = jlo; j0 <= jhi; j0 += 256) {
        int j = j0 + tid;
        float c = 0.f;
        if (j <= jhi) {
            float d = (float)(j - i);
            c = __expf(-d * d * inv) * wb[b * 1024 + j];
        }
        __syncthreads();
        cj[tid] = c;
        __syncthreads();
        int lim = min(256, jhi - j0 + 1);
        for (int t = 0; t < lim; ++t) {
            float cc = cj[t];
            const float* fr = fb + (long)(j0 + t) * 640;
            a0 += cc * fr[tid];
            a1 += cc * fr[tid + 256];
            if (tid < 128) a2 += cc * fr[tid + 512];
        }
    }
    long obase = ((long)b * 1024 + i) * 1280;
    long fbase = ((long)b * 1024 + i) * 640;
    acat[obase + tid] = __float2bfloat16(a0 + feats[fbase + tid]);
    acat[obase + tid + 256] = __float2bfloat16(a1 + feats[fbase + tid + 256]);
    if (tid < 128) acat[obase + tid + 512] = __float2bfloat16(a2 + feats[fbase + tid + 512]);
}

// ---------------------------------------------------------------------------
__global__ void repack_w_k(const float* __restrict__ w, bf16* __restrict__ bt, int CO, int CI)
{
    long idx = (long)blockIdx.x * 256 + threadIdx.x;
    long total = (long)CO * CI * 3;
    if (idx >= total) return;
    int K3 = 3 * CI;
    int o = (int)(idx / K3);
    int k = (int)(idx % K3);
    int t = k / CI, ci = k % CI;
    bt[idx] = __float2bfloat16(w[(long)o * CI * 3 + ci * 3 + t]);
}

__global__ void cast_bf16_k(const float* __restrict__ w, bf16* __restrict__ o, long n)
{
    long idx = (long)blockIdx.x * 256 + threadIdx.x;
    if (idx < n) o[idx] = __float2bfloat16(w[idx]);
}

// ---------------------------------------------------------------------------
extern "C" void kernel_launch(void* const* d_in, const int* in_sizes, int n_in,
                              void* d_out, int out_size, void* d_ws, size_t ws_size,
                              hipStream_t stream)
{
    const float* feats = (const float*)d_in[0];
    const float* cp_w1 = (const float*)d_in[1];
    const float* cp_b1 = (const float*)d_in[2];
    const float* cp_w2 = (const float*)d_in[3];
    const float* cp_b2 = (const float*)d_in[4];
    const float* cp_w3 = (const float*)d_in[5];
    const float* cp_b3 = (const float*)d_in[6];
    const float* cv_w1 = (const float*)d_in[7];
    const float* cv_b1 = (const float*)d_in[8];
    const float* cv_w2 = (const float*)d_in[9];
    const float* cv_b2 = (const float*)d_in[10];
    const float* cv_w3 = (const float*)d_in[11];
    const float* cv_b3 = (const float*)d_in[12];
    const float* mlp_w = (const float*)d_in[13];
    const float* mlp_b = (const float*)d_in[14];
    float* out = (float*)d_out;

    char* ws = (char*)d_ws;
    size_t off = 0;
    auto alloc = [&](size_t bytes) -> char* {
        char* p = ws + off;
        off += (bytes + 255) & ~(size_t)255;
        return p;
    };
    // R1 region: XpadF (21 MB, dead after r1 GEMM) overlaps Acat (42 MB,
    // written only by pool_k / norm_addf, both after r1).
    char* R1 = alloc(16L * 1024 * 1280 * 2);
    bf16* XpadF = (bf16*)R1;
    bf16* Acat = (bf16*)R1;
    bf16* Xp_cp = (bf16*)alloc(16L * 1026 * 1280 * 2);
    bf16* Xp_cv = (bf16*)alloc(16L * 1026 * 1280 * 2);
    bf16* Y0 = (bf16*)alloc(16L * 1024 * 1280 * 2);
    bf16* Y1 = (bf16*)alloc(16L * 1024 * 1280 * 2);
    bf16* Ycv3 = Y0;  // Y0 dead after r2 norm (cp)
    bf16* Bm1 = (bf16*)alloc(2560L * 1920 * 2);
    bf16* Bcp2 = (bf16*)alloc(1280L * 3840 * 2);
    bf16* Bcv2 = (bf16*)alloc(1280L * 3840 * 2);
    bf16* Bcp3 = (bf16*)alloc(2L * 3840 * 2);
    bf16* Bcv3 = (bf16*)alloc(640L * 3840 * 2);
    bf16* Bmlp = (bf16*)alloc(640L * 1280 * 2);
    float* swb = (float*)alloc(16L * 2048 * 4);
    float* stdb = (float*)alloc(16L * 1024 * 4);
    float* wbf = (float*)alloc(16L * 1024 * 4);
    float2* sacc = (float2*)alloc(80L * 8);
    float2* stat = (float2*)alloc(80L * 8);
    (void)ws_size; (void)in_sizes; (void)n_in; (void)out_size;

    const long NF8 = 16L * 1026 * 640 / 8;
    const long N28 = 16L * 1026 * 1280 / 8;
    const long NA8 = 16L * 1024 * 640 / 8;
    const long N1280 = 1024L * 1280, N640 = 1024L * 640;
    const float inv1280 = 1.f / (float)N1280, inv640 = 1.f / (float)N640;

    zero_stats_k<<<1, 128, 0, stream>>>(sacc);
    pack_feats_v_k<<<(NF8 + 255) / 256, 256, 0, stream>>>(feats, XpadF, 640);
    repack_w_k<<<(1280L * 640 * 3 + 255) / 256, 256, 0, stream>>>(cp_w1, Bm1, 1280, 640);
    repack_w_k<<<(1280L * 640 * 3 + 255) / 256, 256, 0, stream>>>(cv_w1, Bm1 + 1280L * 1920, 1280, 640);
    repack_w_k<<<(1280L * 1280 * 3 + 255) / 256, 256, 0, stream>>>(cp_w2, Bcp2, 1280, 1280);
    repack_w_k<<<(1280L * 1280 * 3 + 255) / 256, 256, 0, stream>>>(cv_w2, Bcv2, 1280, 1280);
    repack_w_k<<<(2L * 1280 * 3 + 255) / 256, 256, 0, stream>>>(cp_w3, Bcp3, 2, 1280);
    repack_w_k<<<(640L * 1280 * 3 + 255) / 256, 256, 0, stream>>>(cv_w3, Bcv3, 640, 1280);
    cast_bf16_k<<<(640L * 1280 + 255) / 256, 256, 0, stream>>>(mlp_w, Bmlp, 640L * 1280);

    // ---- round 1: cp1 + cv1 (N-merged, same A) ----
    gemm8_bf16<0><<<640, 512, 0, stream>>>(XpadF, XpadF, Bm1, Bm1 + 1280L * 1920,
                                           cp_b1, cv_b1, Y0, Y1, sacc);
    fin_k<<<1, 64, 0, stream>>>(sacc, stat, inv1280, 32);
    norm_pack_v_k<<<(N28 + 255) / 256, 256, 0, stream>>>(Y0, stat, Xp_cp, 1280);
    norm_pack_v_k<<<(N28 + 255) / 256, 256, 0, stream>>>(Y1, stat + 16, Xp_cv, 1280);

    // ---- round 2: cp2 + cv2 (M-merged) ----
    gemm8_bf16<1><<<640, 512, 0, stream>>>(Xp_cp, Xp_cv, Bcp2, Bcv2,
                                           cp_b2, cv_b2, Y0, Y1, sacc + 32);
    fin_k<<<1, 64, 0, stream>>>(sacc + 32, stat + 32, inv1280, 32);
    norm_pack_v_k<<<(N28 + 255) / 256, 256, 0, stream>>>(Y0, stat + 32, Xp_cp, 1280);
    norm_pack_v_k<<<(N28 + 255) / 256, 256, 0, stream>>>(Y1, stat + 48, Xp_cv, 1280);

    // ---- cp tail: conv3 -> softmaxes -> pooling ----
    conv3cp_k<<<4096, 256, 0, stream>>>(Xp_cp, Bcp3, cp_b3, swb);
    cp_post_k<<<16, 256, 0, stream>>>(swb, stdb, wbf);
    pool_k<<<dim3(1024, 16), 256, 0, stream>>>(feats, stdb, wbf, Acat);

    // ---- cv3 (128^2 kernel) ----
    gemm_bf16<0><<<640, 256, 0, stream>>>(Xp_cv, 1026L * 1280, 1280, Bcv3, cv_b3,
                                          Ycv3, N640, 640, 3840, 5, 8, sacc + 64);
    fin_k<<<1, 64, 0, stream>>>(sacc + 64, stat + 64, inv640, 16);
    norm_addf_v_k<<<(NA8 + 255) / 256, 256, 0, stream>>>(Ycv3, stat + 64, feats, Acat);

    // ---- MLP ----
    gemm_bf16<1><<<640, 256, 0, stream>>>(Acat, N1280, 1280, Bmlp, mlp_b,
                                          out, N640, 640, 1280, 5, 8, nullptr);
}

// Round 5
// 859.813 us; speedup vs baseline: 1.0975x; 1.0975x over previous
//
#include <hip/hip_runtime.h>
#include <hip/hip_bf16.h>
#include <math.h>

#define SLOPE 0.01f
#define EPS_LN 1e-5f

typedef __hip_bfloat16 bf16;
typedef __attribute__((ext_vector_type(8))) short short8;
typedef __attribute__((ext_vector_type(4))) float f32x4;

__device__ __forceinline__ float leakyf(float x) { return x < 0.f ? SLOPE * x : x; }

__device__ __forceinline__ float b2f(short s) {
    unsigned u = ((unsigned)(unsigned short)s) << 16;
    return __builtin_bit_cast(float, u);
}
__device__ __forceinline__ short f2b(float f) {
    __hip_bfloat16 h = __float2bfloat16(f);
    return *(short*)&h;
}

__device__ __forceinline__ void gload_lds16(const void* g, void* l) {
    __builtin_amdgcn_global_load_lds(
        (const __attribute__((address_space(1))) void*)g,
        (__attribute__((address_space(3))) void*)l, 16, 0, 0);
}

// ===========================================================================
// 8-phase 256x256 GEMM (T2+T3+T4+T5), 512 thr = 8 waves (2M x 4N), BK=64.
// LDS: 4 rotating K-half regions per operand (256 rows x 32 K each), 128 KiB.
// region(tile s, khalf kh) = (2s+kh) & 3.
// Race ledger (identical to round-3/4 verified versions):
//   stage schedule per tile s: ph1 A(s+1,k1), ph2 B(s+1,k1), ph3 A(s+2,k0),
//   ph4 B(s+2,k0). vmcnt(8) at end of ph2 gates (s,k1) reads at ph3;
//   vmcnt(8) at end of ph4 gates (s+1,k0) reads at next-tile ph1.
// Round-5 changes (addressing/regime only, ledger unchanged):
//   - bxg-INNER block order (r3/r4 had mt-inner -> A re-fetched 5-10x,
//     FETCH 641 MB, HBM-starved). Now consecutive wids share the A-panel
//     (L2-resident) and sweep B (L3-resident across M-sweeps).
//   - restore lgkmcnt(0)+sched_barrier(0) pin before MFMA (r3 > r4).
// LDS swizzle: phys 16B-chunk P = L ^ ((L>>3)&7), L = row*4 + kg. Involution;
//   staging pre-swizzles the GLOBAL source, LDS dest linear; reads same XOR.
// MODE 0 (r1): K=1920, ldA=640,  NXG=10 (N-merge: branch = bxg>=5)
// MODE 1 (r2): K=3840, ldA=1280, NXG=5  (M-merge: branch = mtg>=64)
// ===========================================================================
#define MM(ai, bi, mm, qq)                                                     \
    acc[mm][qq] = __builtin_amdgcn_mfma_f32_16x16x32_bf16(ai, bi, acc[mm][qq], 0, 0, 0)
#define MFMA16(MB)                                                             \
    MM(a0, bq0, MB + 0, 0); MM(a1, bq0, MB + 1, 0); MM(a2, bq0, MB + 2, 0);    \
    MM(a3, bq0, MB + 3, 0);                                                    \
    MM(a0, bq1, MB + 0, 1); MM(a1, bq1, MB + 1, 1); MM(a2, bq1, MB + 2, 1);    \
    MM(a3, bq1, MB + 3, 1);                                                    \
    MM(a0, bq2, MB + 0, 2); MM(a1, bq2, MB + 1, 2); MM(a2, bq2, MB + 2, 2);    \
    MM(a3, bq2, MB + 3, 2);                                                    \
    MM(a0, bq3, MB + 0, 3); MM(a1, bq3, MB + 1, 3); MM(a2, bq3, MB + 2, 3);    \
    MM(a3, bq3, MB + 3, 3);
#define BARRIER asm volatile("s_barrier" ::: "memory")
#define PIN_LGKM                                                               \
    asm volatile("s_waitcnt lgkmcnt(0)" ::: "memory");                         \
    __builtin_amdgcn_sched_barrier(0);

template <int MODE>
__global__ __launch_bounds__(512, 1) void gemm8_bf16(
    const bf16* __restrict__ A0, const bf16* __restrict__ A1,
    const bf16* __restrict__ Bt0, const bf16* __restrict__ Bt1,
    const float* __restrict__ bias0, const float* __restrict__ bias1,
    bf16* __restrict__ Y0, bf16* __restrict__ Y1,
    float2* __restrict__ sacc)
{
    constexpr int K   = (MODE == 0) ? 1920 : 3840;
    constexpr int LDA = (MODE == 0) ? 640 : 1280;
    constexpr int NXG = (MODE == 0) ? 10 : 5;
    constexpr int NKT = K / 64;

    __shared__ bf16 Ash[4][256][32];
    __shared__ bf16 Bsh[4][256][32];

    const int nwg = gridDim.x;
    const int wid = (blockIdx.x & 7) * (nwg >> 3) + (blockIdx.x >> 3);
    const int bxg = wid % NXG;   // N-tile INNER: A-panel L2-resident
    const int mtg = wid / NXG;
    int branch, bxl, mtl;
    if (MODE == 0) { branch = bxg >= 5; bxl = bxg - branch * 5; mtl = mtg; }
    else           { branch = mtg >= 64; bxl = bxg; mtl = mtg & 63; }
    const int batch = mtl >> 2;
    const int mrow0 = (mtl & 3) * 256;
    const bf16* Apad = branch ? A1 : A0;
    const bf16* Bt   = branch ? Bt1 : Bt0;
    const float* bias = branch ? bias1 : bias0;
    bf16* Yb = branch ? Y1 : Y0;
    const bf16* Abase = Apad + ((long)batch * 1026 + mrow0) * LDA;
    const bf16* Bbase = Bt + (long)bxl * 256 * K;

    const int tid = threadIdx.x;
    const int wave = tid >> 6, lane = tid & 63;
    const int wm = wave >> 2, wn = wave & 3;
    const int r16 = lane & 15, g4 = lane >> 4;

    auto stageA = [&](int s, int kh) {
        char* lb = (char*)&Ash[(2 * s + kh) & 3][0][0];
#pragma unroll
        for (int j = 0; j < 2; ++j) {
            int c = j * 512 + tid;
            int L = c ^ ((c >> 3) & 7);
            int row = L >> 2, kg = L & 3;
            gload_lds16(Abase + (long)row * LDA + (s * 64 + kh * 32 + kg * 8),
                        lb + c * 16);
        }
    };
    auto stageB = [&](int s, int kh) {
        char* lb = (char*)&Bsh[(2 * s + kh) & 3][0][0];
#pragma unroll
        for (int j = 0; j < 2; ++j) {
            int c = j * 512 + tid;
            int L = c ^ ((c >> 3) & 7);
            int row = L >> 2, kg = L & 3;
            gload_lds16(Bbase + (long)row * K + (s * 64 + kh * 32 + kg * 8),
                        lb + c * 16);
        }
    };
    auto ldA8 = [&](int reg, int mi) -> short8 {
        int row = wm * 128 + mi * 16 + r16;
        int P = ((row << 2) | g4) ^ ((row >> 1) & 7);
        return *(const short8*)((const char*)&Ash[reg][0][0] + P * 16);
    };
    auto ldB8 = [&](int reg, int q) -> short8 {
        int row = wn * 64 + q * 16 + r16;
        int P = ((row << 2) | g4) ^ ((row >> 1) & 7);
        return *(const short8*)((const char*)&Bsh[reg][0][0] + P * 16);
    };

    f32x4 acc[8][4];
#pragma unroll
    for (int i = 0; i < 8; ++i)
#pragma unroll
        for (int j = 0; j < 4; ++j) acc[i][j] = (f32x4){0.f, 0.f, 0.f, 0.f};

    // prologue: events (0,A,k0)(0,B,k0)(0,A,k1)(0,B,k1)(1,A,k0)(1,B,k0)
    stageA(0, 0); stageB(0, 0);
    stageA(0, 1); stageB(0, 1);
    stageA(1, 0); stageB(1, 0);
    asm volatile("s_waitcnt vmcnt(8)" ::: "memory");  // (0,k0) landed
    BARRIER;

    for (int s = 0; s < NKT; ++s) {
        const int rA = (2 * s) & 3;
        const int rB = (2 * s + 1) & 3;
        short8 a0, a1, a2, a3, bq0, bq1, bq2, bq3;
        // phase 1: kh=0, mi 0-3 (+ all B for kh=0)
        a0 = ldA8(rA, 0); bq0 = ldB8(rA, 0);
        a1 = ldA8(rA, 1); bq1 = ldB8(rA, 1);
        a2 = ldA8(rA, 2); bq2 = ldB8(rA, 2);
        a3 = ldA8(rA, 3); bq3 = ldB8(rA, 3);
        if (s + 1 < NKT) stageA(s + 1, 1);
        BARRIER;
        PIN_LGKM
        __builtin_amdgcn_s_setprio(1);
        MFMA16(0)
        __builtin_amdgcn_s_setprio(0);
        BARRIER;
        // phase 2: kh=0, mi 4-7 (B held in regs)
        a0 = ldA8(rA, 4); a1 = ldA8(rA, 5); a2 = ldA8(rA, 6); a3 = ldA8(rA, 7);
        if (s + 1 < NKT) stageB(s + 1, 1);
        BARRIER;
        PIN_LGKM
        __builtin_amdgcn_s_setprio(1);
        MFMA16(4)
        __builtin_amdgcn_s_setprio(0);
        asm volatile("s_waitcnt vmcnt(8)" ::: "memory");  // gate (s,k1)
        BARRIER;
        // phase 3: kh=1, mi 0-3
        a0 = ldA8(rB, 0); bq0 = ldB8(rB, 0);
        a1 = ldA8(rB, 1); bq1 = ldB8(rB, 1);
        a2 = ldA8(rB, 2); bq2 = ldB8(rB, 2);
        a3 = ldA8(rB, 3); bq3 = ldB8(rB, 3);
        if (s + 2 < NKT) stageA(s + 2, 0);
        BARRIER;
        PIN_LGKM
        __builtin_amdgcn_s_setprio(1);
        MFMA16(0)
        __builtin_amdgcn_s_setprio(0);
        BARRIER;
        // phase 4: kh=1, mi 4-7
        a0 = ldA8(rB, 4); a1 = ldA8(rB, 5); a2 = ldA8(rB, 6); a3 = ldA8(rB, 7);
        if (s + 2 < NKT) stageB(s + 2, 0);
        BARRIER;
        PIN_LGKM
        __builtin_amdgcn_s_setprio(1);
        MFMA16(4)
        __builtin_amdgcn_s_setprio(0);
        asm volatile("s_waitcnt vmcnt(8)" ::: "memory");  // gate (s+1,k0)
        BARRIER;
    }
    asm volatile("s_waitcnt vmcnt(0) lgkmcnt(0)" ::: "memory");

    float ssum = 0.f, sq = 0.f;
#pragma unroll
    for (int mi = 0; mi < 8; ++mi) {
#pragma unroll
        for (int q = 0; q < 4; ++q) {
            int col = bxl * 256 + wn * 64 + q * 16 + r16;
            float bv = bias[col];
#pragma unroll
            for (int rr = 0; rr < 4; ++rr) {
                int row = mrow0 + wm * 128 + mi * 16 + g4 * 4 + rr;
                float v = acc[mi][q][rr] + bv;
                Yb[((long)batch * 1024 + row) * 1280 + col] = __float2bfloat16(v);
                ssum += v; sq += v * v;
            }
        }
    }
    __syncthreads();
    float* red = (float*)&Ash[0][0][0];
    red[tid] = ssum; red[512 + tid] = sq;
    __syncthreads();
    for (int o = 256; o; o >>= 1) {
        if (tid < o) { red[tid] += red[tid + o]; red[512 + tid] += red[512 + tid + o]; }
        __syncthreads();
    }
    if (tid == 0) {
        atomicAdd(&sacc[branch * 16 + batch].x, red[0]);
        atomicAdd(&sacc[branch * 16 + batch].y, red[512]);
    }
}

// ---------------------------------------------------------------------------
// 128x128 2-phase GEMM (round-2 proven) — used for cv3 and MLP.
// ---------------------------------------------------------------------------
template <int EPI>
__global__ __launch_bounds__(256, 2) void gemm_bf16(
    const bf16* __restrict__ A, long sA, int ldA,
    const bf16* __restrict__ Bt,
    const float* __restrict__ bias,
    void* __restrict__ Outv, long sO, int ldO, int K,
    int gx, int gy, float2* __restrict__ stats)
{
    __shared__ bf16 As[128][64];
    __shared__ bf16 Bs[128][64];

    const int nwg = gridDim.x;
    const int wid = (blockIdx.x & 7) * (nwg >> 3) + (blockIdx.x >> 3);
    const int bx = wid % gx;
    const int by = (wid / gx) % gy;
    const int bz = wid / (gx * gy);

    const bf16* Ab = A + (long)bz * sA + (long)by * 128 * ldA;
    const bf16* Bb = Bt + (long)bx * 128 * K;
    const int tid = threadIdx.x;
    const int wave = tid >> 6, lane = tid & 63;
    const int moff = (wave >> 1) * 64, noff = (wave & 1) * 64;
    const int r16 = lane & 15, g4 = lane >> 4;
    const int r7 = r16 & 7;

    f32x4 acc[4][4];
#pragma unroll
    for (int i = 0; i < 4; ++i)
#pragma unroll
        for (int j = 0; j < 4; ++j)
            acc[i][j] = (f32x4){0.f, 0.f, 0.f, 0.f};

    for (int k0 = 0; k0 < K; k0 += 64) {
        __syncthreads();
#pragma unroll
        for (int i = 0; i < 4; ++i) {
            int chunk = i * 256 + tid;
            int row = chunk >> 3;
            int kc = (chunk ^ (chunk >> 3)) & 7;
            gload_lds16(Ab + (long)row * ldA + (k0 + kc * 8),
                        (char*)(&As[0][0]) + (i * 256 + wave * 64) * 16);
        }
#pragma unroll
        for (int i = 0; i < 4; ++i) {
            int chunk = i * 256 + tid;
            int row = chunk >> 3;
            int kc = (chunk ^ (chunk >> 3)) & 7;
            gload_lds16(Bb + (long)row * K + (k0 + kc * 8),
                        (char*)(&Bs[0][0]) + (i * 256 + wave * 64) * 16);
        }
        __syncthreads();
#pragma unroll
        for (int kk = 0; kk < 2; ++kk) {
            short8 af[4], bfr[4];
#pragma unroll
            for (int mi = 0; mi < 4; ++mi)
                af[mi] = *(const short8*)&As[moff + mi * 16 + r16][((kk * 4 + g4) ^ r7) * 8];
#pragma unroll
            for (int ni = 0; ni < 4; ++ni)
                bfr[ni] = *(const short8*)&Bs[noff + ni * 16 + r16][((kk * 4 + g4) ^ r7) * 8];
#pragma unroll
            for (int mi = 0; mi < 4; ++mi)
#pragma unroll
                for (int ni = 0; ni < 4; ++ni)
                    acc[mi][ni] = __builtin_amdgcn_mfma_f32_16x16x32_bf16(
                        af[mi], bfr[ni], acc[mi][ni], 0, 0, 0);
        }
    }

    float s = 0.f, q = 0.f;
#pragma unroll
    for (int mi = 0; mi < 4; ++mi) {
#pragma unroll
        for (int ni = 0; ni < 4; ++ni) {
            int col = bx * 128 + noff + ni * 16 + r16;
            float bv = bias[col];
#pragma unroll
            for (int r = 0; r < 4; ++r) {
                int row = by * 128 + moff + mi * 16 + g4 * 4 + r;
                float v = acc[mi][ni][r] + bv;
                if (EPI == 1) {
                    ((float*)Outv)[(long)bz * sO + (long)row * ldO + col] = leakyf(v);
                } else {
                    ((bf16*)Outv)[(long)bz * sO + (long)row * ldO + col] = __float2bfloat16(v);
                    s += v; q += v * v;
                }
            }
        }
    }
    if (EPI == 0) {
        __syncthreads();
        float* red = (float*)&As[0][0];
        float* red2 = red + 256;
        red[tid] = s; red2[tid] = q;
        __syncthreads();
        for (int o = 128; o; o >>= 1) {
            if (tid < o) { red[tid] += red[tid + o]; red2[tid] += red2[tid + o]; }
            __syncthreads();
        }
        if (tid == 0) {
            atomicAdd(&stats[bz].x, red[0]);
            atomicAdd(&stats[bz].y, red2[0]);
        }
    }
}

// ---------------------------------------------------------------------------
__global__ void zero_stats_k(float2* s) {
    if (threadIdx.x < 80) s[threadIdx.x] = make_float2(0.f, 0.f);
}

__global__ void fin_k(const float2* __restrict__ acc, float2* __restrict__ stat,
                      float invN, int n) {
    int b = threadIdx.x;
    if (b < n) {
        float m = acc[b].x * invN;
        float var = acc[b].y * invN - m * m;
        stat[b] = make_float2(m, rsqrtf(var + EPS_LN));
    }
}

// ---------------------------------------------------------------------------
__global__ void pack_feats_v_k(const float* __restrict__ f, bf16* __restrict__ xp, int C)
{
    long i8 = (long)blockIdx.x * 256 + threadIdx.x;
    long total8 = 16L * 1026 * C / 8;
    if (i8 >= total8) return;
    long e = i8 * 8;
    int c = (int)(e % C);
    long t = e / C;
    int r = (int)(t % 1026);
    int b = (int)(t / 1026);
    short8 o;
    if (r == 0 || r == 1025) {
#pragma unroll
        for (int j = 0; j < 8; ++j) o[j] = 0;
    } else {
        const float* src = f + ((long)b * 1024 + (r - 1)) * C + c;
        f32x4 v0 = *(const f32x4*)src;
        f32x4 v1 = *(const f32x4*)(src + 4);
#pragma unroll
        for (int j = 0; j < 4; ++j) { o[j] = f2b(v0[j]); o[j + 4] = f2b(v1[j]); }
    }
    *(short8*)(xp + e) = o;
}

__global__ void norm_pack_v_k(const bf16* __restrict__ y, const float2* __restrict__ stat,
                              bf16* __restrict__ xp, int C)
{
    long i8 = (long)blockIdx.x * 256 + threadIdx.x;
    long total8 = 16L * 1026 * C / 8;
    if (i8 >= total8) return;
    long e = i8 * 8;
    int c = (int)(e % C);
    long t = e / C;
    int r = (int)(t % 1026);
    int b = (int)(t / 1026);
    short8 o;
    if (r == 0 || r == 1025) {
#pragma unroll
        for (int j = 0; j < 8; ++j) o[j] = 0;
    } else {
        float2 st = stat[b];
        short8 v = *(const short8*)(y + ((long)b * 1024 + (r - 1)) * C + c);
#pragma unroll
        for (int j = 0; j < 8; ++j)
            o[j] = f2b(leakyf((b2f(v[j]) - st.x) * st.y));
    }
    *(short8*)(xp + e) = o;
}

__global__ void norm_addf_v_k(const bf16* __restrict__ y, const float2* __restrict__ stat,
                              const float* __restrict__ feats, bf16* __restrict__ acat)
{
    long i8 = (long)blockIdx.x * 256 + threadIdx.x;
    long total8 = 16L * 1024 * 640 / 8;
    if (i8 >= total8) return;
    long e = i8 * 8;
    int c = (int)(e % 640);
    int l = (int)((e / 640) % 1024);
    int b = (int)(e / (640L * 1024));
    float2 st = stat[b];
    short8 v = *(const short8*)(y + e);
    f32x4 f0 = *(const f32x4*)(feats + e);
    f32x4 f1 = *(const f32x4*)(feats + e + 4);
    short8 o;
#pragma unroll
    for (int j = 0; j < 4; ++j) {
        o[j] = f2b(leakyf((b2f(v[j]) - st.x) * st.y) + f0[j]);
        o[j + 4] = f2b(leakyf((b2f(v[j + 4]) - st.x) * st.y) + f1[j]);
    }
    *(short8*)(acat + ((long)b * 1024 + l) * 1280 + 640 + c) = o;
}

// ---------------------------------------------------------------------------
// cp conv3 (N=2): one wave per (b,l), short8-vectorized.
// ---------------------------------------------------------------------------
__global__ void conv3cp_k(const bf16* __restrict__ xp, const bf16* __restrict__ w3,
                          const float* __restrict__ b3, float* __restrict__ sw)
{
    int wid = (int)((blockIdx.x * 256 + threadIdx.x) >> 6);
    int lane = threadIdx.x & 63;
    int b = wid >> 10, l = wid & 1023;
    const short8* xr = (const short8*)(xp + ((long)b * 1026 + l) * 1280);
    const short8* w0 = (const short8*)w3;
    const short8* w1 = (const short8*)(w3 + 3840);
    float a0 = 0.f, a1 = 0.f;
    for (int c = lane; c < 480; c += 64) {
        short8 x = xr[c], u = w0[c], v = w1[c];
#pragma unroll
        for (int j = 0; j < 8; ++j) {
            float xf = b2f(x[j]);
            a0 += xf * b2f(u[j]);
            a1 += xf * b2f(v[j]);
        }
    }
    for (int o = 32; o; o >>= 1) { a0 += __shfl_down(a0, o); a1 += __shfl_down(a1, o); }
    if (lane == 0) {
        sw[b * 2048 + l] = a0 + b3[0];
        sw[b * 2048 + 1024 + l] = a1 + b3[1];
    }
}

// ---------------------------------------------------------------------------
__global__ __launch_bounds__(256) void cp_post_k(const float* __restrict__ sw,
                                                 float* __restrict__ stdb,
                                                 float* __restrict__ wb)
{
    int b = blockIdx.x, tid = threadIdx.x;
    __shared__ float s0[1024], s1[1024], red[256];
    const float* p = sw + b * 2048;
    float s = 0.f, q = 0.f;
    for (int l = tid; l < 1024; l += 256) {
        float v0 = p[l], v1 = p[1024 + l];
        s0[l] = v0; s1[l] = v1;
        s += v0 + v1; q += v0 * v0 + v1 * v1;
    }
    red[tid] = s; __syncthreads();
    for (int o = 128; o; o >>= 1) { if (tid < o) red[tid] += red[tid + o]; __syncthreads(); }
    float mean = red[0] / 2048.f; __syncthreads();
    red[tid] = q; __syncthreads();
    for (int o = 128; o; o >>= 1) { if (tid < o) red[tid] += red[tid + o]; __syncthreads(); }
    float inv = rsqrtf(red[0] / 2048.f - mean * mean + EPS_LN); __syncthreads();
    for (int l = tid; l < 1024; l += 256) {
        s0[l] = leakyf((s0[l] - mean) * inv);
        s1[l] = leakyf((s1[l] - mean) * inv);
    }
    __syncthreads();
    float mx = -1e30f;
    for (int l = tid; l < 1024; l += 256) mx = fmaxf(mx, s0[l]);
    red[tid] = mx; __syncthreads();
    for (int o = 128; o; o >>= 1) { if (tid < o) red[tid] = fmaxf(red[tid], red[tid + o]); __syncthreads(); }
    mx = red[0]; __syncthreads();
    float se = 0.f;
    for (int l = tid; l < 1024; l += 256) { float e = __expf(s0[l] - mx); s0[l] = e; se += e; }
    red[tid] = se; __syncthreads();
    for (int o = 128; o; o >>= 1) { if (tid < o) red[tid] += red[tid + o]; __syncthreads(); }
    float rs = 1.f / red[0]; __syncthreads();
    for (int l = tid; l < 1024; l += 256) stdb[b * 1024 + l] = 102.4f * s0[l] * rs;
    mx = -1e30f;
    for (int l = tid; l < 1024; l += 256) mx = fmaxf(mx, s1[l]);
    red[tid] = mx; __syncthreads();
    for (int o = 128; o; o >>= 1) { if (tid < o) red[tid] = fmaxf(red[tid], red[tid + o]); __syncthreads(); }
    mx = red[0]; __syncthreads();
    se = 0.f;
    for (int l = tid; l < 1024; l += 256) { float e = __expf(s1[l] - mx); s1[l] = e; se += e; }
    red[tid] = se; __syncthreads();
    for (int o = 128; o; o >>= 1) { if (tid < o) red[tid] += red[tid + o]; __syncthreads(); }
    rs = 1.f / red[0]; __syncthreads();
    for (int l = tid; l < 1024; l += 256) wb[b * 1024 + l] = s1[l] * rs;
}

// ---------------------------------------------------------------------------
__global__ __launch_bounds__(256) void pool_k(const float* __restrict__ feats,
                                              const float* __restrict__ stdb,
                                              const float* __restrict__ wb,
                                              bf16* __restrict__ acat)
{
    int i = blockIdx.x, b = blockIdx.y, tid = threadIdx.x;
    float sd = stdb[b * 1024 + i];
    float den = 1e-5f + 2.f * sd * sd;
    float inv = 1.f / den;
    int R = (int)sqrtf(11.5129255f * den) + 1;
    int jlo = max(0, i - R), jhi = min(1023, i + R);
    __shared__ float cj[256];
    float a0 = 0.f, a1 = 0.f, a2 = 0.f;
    const float* fb = feats + (long)b * 1024 * 640;
    for (int j0 = jlo; j0 <= jhi; j0 += 256) {
        int j = j0 + tid;
        float c = 0.f;
        if (j <= jhi) {
            float d = (float)(j - i);
            c = __expf(-d * d * inv) * wb[b * 1024 + j];
        }
        __syncthreads();
        cj[tid] = c;
        __syncthreads();
        int lim = min(256, jhi - j0 + 1);
        for (int t = 0; t < lim; ++t) {
            float cc = cj[t];
            const float* fr = fb + (long)(j0 + t) * 640;
            a0 += cc * fr[tid];
            a1 += cc * fr[tid + 256];
            if (tid < 128) a2 += cc * fr[tid + 512];
        }
    }
    long obase = ((long)b * 1024 + i) * 1280;
    long fbase = ((long)b * 1024 + i) * 640;
    acat[obase + tid] = __float2bfloat16(a0 + feats[fbase + tid]);
    acat[obase + tid + 256] = __float2bfloat16(a1 + feats[fbase + tid + 256]);
    if (tid < 128) acat[obase + tid + 512] = __float2bfloat16(a2 + feats[fbase + tid + 512]);
}

// ---------------------------------------------------------------------------
__global__ void repack_w_k(const float* __restrict__ w, bf16* __restrict__ bt, int CO, int CI)
{
    long idx = (long)blockIdx.x * 256 + threadIdx.x;
    long total = (long)CO * CI * 3;
    if (idx >= total) return;
    int K3 = 3 * CI;
    int o = (int)(idx / K3);
    int k = (int)(idx % K3);
    int t = k / CI, ci = k % CI;
    bt[idx] = __float2bfloat16(w[(long)o * CI * 3 + ci * 3 + t]);
}

__global__ void cast_bf16_k(const float* __restrict__ w, bf16* __restrict__ o, long n)
{
    long idx = (long)blockIdx.x * 256 + threadIdx.x;
    if (idx < n) o[idx] = __float2bfloat16(w[idx]);
}

// ---------------------------------------------------------------------------
extern "C" void kernel_launch(void* const* d_in, const int* in_sizes, int n_in,
                              void* d_out, int out_size, void* d_ws, size_t ws_size,
                              hipStream_t stream)
{
    const float* feats = (const float*)d_in[0];
    const float* cp_w1 = (const float*)d_in[1];
    const float* cp_b1 = (const float*)d_in[2];
    const float* cp_w2 = (const float*)d_in[3];
    const float* cp_b2 = (const float*)d_in[4];
    const float* cp_w3 = (const float*)d_in[5];
    const float* cp_b3 = (const float*)d_in[6];
    const float* cv_w1 = (const float*)d_in[7];
    const float* cv_b1 = (const float*)d_in[8];
    const float* cv_w2 = (const float*)d_in[9];
    const float* cv_b2 = (const float*)d_in[10];
    const float* cv_w3 = (const float*)d_in[11];
    const float* cv_b3 = (const float*)d_in[12];
    const float* mlp_w = (const float*)d_in[13];
    const float* mlp_b = (const float*)d_in[14];
    float* out = (float*)d_out;

    char* ws = (char*)d_ws;
    size_t off = 0;
    auto alloc = [&](size_t bytes) -> char* {
        char* p = ws + off;
        off += (bytes + 255) & ~(size_t)255;
        return p;
    };
    // R1 region: XpadF (21 MB, dead after r1 GEMM) overlaps Acat (42 MB,
    // written only by pool_k / norm_addf, both after r1).
    char* R1 = alloc(16L * 1024 * 1280 * 2);
    bf16* XpadF = (bf16*)R1;
    bf16* Acat = (bf16*)R1;
    bf16* Xp_cp = (bf16*)alloc(16L * 1026 * 1280 * 2);
    bf16* Xp_cv = (bf16*)alloc(16L * 1026 * 1280 * 2);
    bf16* Y0 = (bf16*)alloc(16L * 1024 * 1280 * 2);
    bf16* Y1 = (bf16*)alloc(16L * 1024 * 1280 * 2);
    bf16* Ycv3 = Y0;  // Y0 dead after r2 norm (cp)
    bf16* Bm1 = (bf16*)alloc(2560L * 1920 * 2);
    bf16* Bcp2 = (bf16*)alloc(1280L * 3840 * 2);
    bf16* Bcv2 = (bf16*)alloc(1280L * 3840 * 2);
    bf16* Bcp3 = (bf16*)alloc(2L * 3840 * 2);
    bf16* Bcv3 = (bf16*)alloc(640L * 3840 * 2);
    bf16* Bmlp = (bf16*)alloc(640L * 1280 * 2);
    float* swb = (float*)alloc(16L * 2048 * 4);
    float* stdb = (float*)alloc(16L * 1024 * 4);
    float* wbf = (float*)alloc(16L * 1024 * 4);
    float2* sacc = (float2*)alloc(80L * 8);
    float2* stat = (float2*)alloc(80L * 8);
    (void)ws_size; (void)in_sizes; (void)n_in; (void)out_size;

    const long NF8 = 16L * 1026 * 640 / 8;
    const long N28 = 16L * 1026 * 1280 / 8;
    const long NA8 = 16L * 1024 * 640 / 8;
    const long N1280 = 1024L * 1280, N640 = 1024L * 640;
    const float inv1280 = 1.f / (float)N1280, inv640 = 1.f / (float)N640;

    zero_stats_k<<<1, 128, 0, stream>>>(sacc);
    pack_feats_v_k<<<(NF8 + 255) / 256, 256, 0, stream>>>(feats, XpadF, 640);
    repack_w_k<<<(1280L * 640 * 3 + 255) / 256, 256, 0, stream>>>(cp_w1, Bm1, 1280, 640);
    repack_w_k<<<(1280L * 640 * 3 + 255) / 256, 256, 0, stream>>>(cv_w1, Bm1 + 1280L * 1920, 1280, 640);
    repack_w_k<<<(1280L * 1280 * 3 + 255) / 256, 256, 0, stream>>>(cp_w2, Bcp2, 1280, 1280);
    repack_w_k<<<(1280L * 1280 * 3 + 255) / 256, 256, 0, stream>>>(cv_w2, Bcv2, 1280, 1280);
    repack_w_k<<<(2L * 1280 * 3 + 255) / 256, 256, 0, stream>>>(cp_w3, Bcp3, 2, 1280);
    repack_w_k<<<(640L * 1280 * 3 + 255) / 256, 256, 0, stream>>>(cv_w3, Bcv3, 640, 1280);
    cast_bf16_k<<<(640L * 1280 + 255) / 256, 256, 0, stream>>>(mlp_w, Bmlp, 640L * 1280);

    // ---- round 1: cp1 + cv1 (N-merged, same A) ----
    gemm8_bf16<0><<<640, 512, 0, stream>>>(XpadF, XpadF, Bm1, Bm1 + 1280L * 1920,
                                           cp_b1, cv_b1, Y0, Y1, sacc);
    fin_k<<<1, 64, 0, stream>>>(sacc, stat, inv1280, 32);
    norm_pack_v_k<<<(N28 + 255) / 256, 256, 0, stream>>>(Y0, stat, Xp_cp, 1280);
    norm_pack_v_k<<<(N28 + 255) / 256, 256, 0, stream>>>(Y1, stat + 16, Xp_cv, 1280);

    // ---- round 2: cp2 + cv2 (M-merged) ----
    gemm8_bf16<1><<<640, 512, 0, stream>>>(Xp_cp, Xp_cv, Bcp2, Bcv2,
                                           cp_b2, cv_b2, Y0, Y1, sacc + 32);
    fin_k<<<1, 64, 0, stream>>>(sacc + 32, stat + 32, inv1280, 32);
    norm_pack_v_k<<<(N28 + 255) / 256, 256, 0, stream>>>(Y0, stat + 32, Xp_cp, 1280);
    norm_pack_v_k<<<(N28 + 255) / 256, 256, 0, stream>>>(Y1, stat + 48, Xp_cv, 1280);

    // ---- cp tail: conv3 -> softmaxes -> pooling ----
    conv3cp_k<<<4096, 256, 0, stream>>>(Xp_cp, Bcp3, cp_b3, swb);
    cp_post_k<<<16, 256, 0, stream>>>(swb, stdb, wbf);
    pool_k<<<dim3(1024, 16), 256, 0, stream>>>(feats, stdb, wbf, Acat);

    // ---- cv3 (128^2 kernel) ----
    gemm_bf16<0><<<640, 256, 0, stream>>>(Xp_cv, 1026L * 1280, 1280, Bcv3, cv_b3,
                                          Ycv3, N640, 640, 3840, 5, 8, sacc + 64);
    fin_k<<<1, 64, 0, stream>>>(sacc + 64, stat + 64, inv640, 16);
    norm_addf_v_k<<<(NA8 + 255) / 256, 256, 0, stream>>>(Ycv3, stat + 64, feats, Acat);

    // ---- MLP ----
    gemm_bf16<1><<<640, 256, 0, stream>>>(Acat, N1280, 1280, Bmlp, mlp_b,
                                          out, N640, 640, 1280, 5, 8, nullptr);
}

// Round 6
// 787.294 us; speedup vs baseline: 1.1986x; 1.0921x over previous
//
#include <hip/hip_runtime.h>
#include <hip/hip_bf16.h>
#include <math.h>

#define SLOPE 0.01f
#define EPS_LN 1e-5f

typedef __hip_bfloat16 bf16;
typedef __attribute__((ext_vector_type(8))) short short8;
typedef __attribute__((ext_vector_type(4))) float f32x4;

__device__ __forceinline__ float leakyf(float x) { return x < 0.f ? SLOPE * x : x; }

__device__ __forceinline__ float b2f(short s) {
    unsigned u = ((unsigned)(unsigned short)s) << 16;
    return __builtin_bit_cast(float, u);
}
__device__ __forceinline__ short f2b(float f) {
    __hip_bfloat16 h = __float2bfloat16(f);
    return *(short*)&h;
}

__device__ __forceinline__ void gload_lds16(const void* g, void* l) {
    __builtin_amdgcn_global_load_lds(
        (const __attribute__((address_space(1))) void*)g,
        (__attribute__((address_space(3))) void*)l, 16, 0, 0);
}

// ---------------------------------------------------------------------------
// 2-phase 128x128 GEMM (round-2 proven, 920 TF) with DUAL-problem branch:
// wid >= halfwg selects problem 1 (merges cp+cv layers into one dispatch so
// the grid is a multiple of 512 = 2 wg/CU x 256 CU -> no tail round).
// T2 LDS swizzle (pre-swizzled global source + XOR'd ds_read, conflict-free),
// T1 XCD-chunked bid swizzle (nwg % 8 == 0 always).
// EPI 0: out bf16 + per-batch sum/sumsq atomics (fused LN stats)
// EPI 1: out f32, bias + leaky (final MLP)
// ---------------------------------------------------------------------------
template <int EPI>
__global__ __launch_bounds__(256, 2) void gemm_dual(
    const bf16* __restrict__ A0, const bf16* __restrict__ A1, long sA, int ldA,
    const bf16* __restrict__ Bt0, const bf16* __restrict__ Bt1,
    const float* __restrict__ bias0, const float* __restrict__ bias1,
    void* __restrict__ Out0, void* __restrict__ Out1, long sO, int ldO, int K,
    int gx, int gy, int halfwg,
    float2* __restrict__ stats0, float2* __restrict__ stats1)
{
    __shared__ bf16 As[128][64];
    __shared__ bf16 Bs[128][64];

    const int nwg = gridDim.x;
    const int wid = (blockIdx.x & 7) * (nwg >> 3) + (blockIdx.x >> 3);
    const int branch = wid >= halfwg;
    const int w = wid - branch * halfwg;
    const int bx = w % gx;                 // bx-inner: A-panel L2-resident
    const int by = (w / gx) % gy;
    const int bz = w / (gx * gy);

    const bf16* A = branch ? A1 : A0;
    const bf16* Bt = branch ? Bt1 : Bt0;
    const float* bias = branch ? bias1 : bias0;
    void* Outv = branch ? Out1 : Out0;
    float2* stats = branch ? stats1 : stats0;

    const bf16* Ab = A + (long)bz * sA + (long)by * 128 * ldA;
    const bf16* Bb = Bt + (long)bx * 128 * K;
    const int tid = threadIdx.x;
    const int wave = tid >> 6, lane = tid & 63;
    const int moff = (wave >> 1) * 64, noff = (wave & 1) * 64;
    const int r16 = lane & 15, g4 = lane >> 4;
    const int r7 = r16 & 7;

    f32x4 acc[4][4];
#pragma unroll
    for (int i = 0; i < 4; ++i)
#pragma unroll
        for (int j = 0; j < 4; ++j)
            acc[i][j] = (f32x4){0.f, 0.f, 0.f, 0.f};

    for (int k0 = 0; k0 < K; k0 += 64) {
        __syncthreads();
#pragma unroll
        for (int i = 0; i < 4; ++i) {
            int chunk = i * 256 + tid;
            int row = chunk >> 3;
            int kc = (chunk ^ (chunk >> 3)) & 7;
            gload_lds16(Ab + (long)row * ldA + (k0 + kc * 8),
                        (char*)(&As[0][0]) + (i * 256 + wave * 64) * 16);
        }
#pragma unroll
        for (int i = 0; i < 4; ++i) {
            int chunk = i * 256 + tid;
            int row = chunk >> 3;
            int kc = (chunk ^ (chunk >> 3)) & 7;
            gload_lds16(Bb + (long)row * K + (k0 + kc * 8),
                        (char*)(&Bs[0][0]) + (i * 256 + wave * 64) * 16);
        }
        __syncthreads();
#pragma unroll
        for (int kk = 0; kk < 2; ++kk) {
            short8 af[4], bfr[4];
#pragma unroll
            for (int mi = 0; mi < 4; ++mi)
                af[mi] = *(const short8*)&As[moff + mi * 16 + r16][((kk * 4 + g4) ^ r7) * 8];
#pragma unroll
            for (int ni = 0; ni < 4; ++ni)
                bfr[ni] = *(const short8*)&Bs[noff + ni * 16 + r16][((kk * 4 + g4) ^ r7) * 8];
#pragma unroll
            for (int mi = 0; mi < 4; ++mi)
#pragma unroll
                for (int ni = 0; ni < 4; ++ni)
                    acc[mi][ni] = __builtin_amdgcn_mfma_f32_16x16x32_bf16(
                        af[mi], bfr[ni], acc[mi][ni], 0, 0, 0);
        }
    }

    float s = 0.f, q = 0.f;
#pragma unroll
    for (int mi = 0; mi < 4; ++mi) {
#pragma unroll
        for (int ni = 0; ni < 4; ++ni) {
            int col = bx * 128 + noff + ni * 16 + r16;
            float bv = bias[col];
#pragma unroll
            for (int r = 0; r < 4; ++r) {
                int row = by * 128 + moff + mi * 16 + g4 * 4 + r;
                float v = acc[mi][ni][r] + bv;
                if (EPI == 1) {
                    ((float*)Outv)[(long)bz * sO + (long)row * ldO + col] = leakyf(v);
                } else {
                    ((bf16*)Outv)[(long)bz * sO + (long)row * ldO + col] = __float2bfloat16(v);
                    s += v; q += v * v;
                }
            }
        }
    }
    if (EPI == 0) {
        __syncthreads();
        float* red = (float*)&As[0][0];
        float* red2 = red + 256;
        red[tid] = s; red2[tid] = q;
        __syncthreads();
        for (int o = 128; o; o >>= 1) {
            if (tid < o) { red[tid] += red[tid + o]; red2[tid] += red2[tid + o]; }
            __syncthreads();
        }
        if (tid == 0) {
            atomicAdd(&stats[bz].x, red[0]);
            atomicAdd(&stats[bz].y, red2[0]);
        }
    }
}

// ---------------------------------------------------------------------------
__global__ void zero_stats_k(float2* s) {
    if (threadIdx.x < 80) s[threadIdx.x] = make_float2(0.f, 0.f);
}

__global__ void fin_k(const float2* __restrict__ acc, float2* __restrict__ stat,
                      float invN, int n) {
    int b = threadIdx.x;
    if (b < n) {
        float m = acc[b].x * invN;
        float var = acc[b].y * invN - m * m;
        stat[b] = make_float2(m, rsqrtf(var + EPS_LN));
    }
}

// ---------------------------------------------------------------------------
__global__ void pack_feats_v_k(const float* __restrict__ f, bf16* __restrict__ xp, int C)
{
    long i8 = (long)blockIdx.x * 256 + threadIdx.x;
    long total8 = 16L * 1026 * C / 8;
    if (i8 >= total8) return;
    long e = i8 * 8;
    int c = (int)(e % C);
    long t = e / C;
    int r = (int)(t % 1026);
    int b = (int)(t / 1026);
    short8 o;
    if (r == 0 || r == 1025) {
#pragma unroll
        for (int j = 0; j < 8; ++j) o[j] = 0;
    } else {
        const float* src = f + ((long)b * 1024 + (r - 1)) * C + c;
        f32x4 v0 = *(const f32x4*)src;
        f32x4 v1 = *(const f32x4*)(src + 4);
#pragma unroll
        for (int j = 0; j < 4; ++j) { o[j] = f2b(v0[j]); o[j + 4] = f2b(v1[j]); }
    }
    *(short8*)(xp + e) = o;
}

__global__ void norm_pack_v_k(const bf16* __restrict__ y, const float2* __restrict__ stat,
                              bf16* __restrict__ xp, int C)
{
    long i8 = (long)blockIdx.x * 256 + threadIdx.x;
    long total8 = 16L * 1026 * C / 8;
    if (i8 >= total8) return;
    long e = i8 * 8;
    int c = (int)(e % C);
    long t = e / C;
    int r = (int)(t % 1026);
    int b = (int)(t / 1026);
    short8 o;
    if (r == 0 || r == 1025) {
#pragma unroll
        for (int j = 0; j < 8; ++j) o[j] = 0;
    } else {
        float2 st = stat[b];
        short8 v = *(const short8*)(y + ((long)b * 1024 + (r - 1)) * C + c);
#pragma unroll
        for (int j = 0; j < 8; ++j)
            o[j] = f2b(leakyf((b2f(v[j]) - st.x) * st.y));
    }
    *(short8*)(xp + e) = o;
}

__global__ void norm_addf_v_k(const bf16* __restrict__ y, const float2* __restrict__ stat,
                              const float* __restrict__ feats, bf16* __restrict__ acat)
{
    long i8 = (long)blockIdx.x * 256 + threadIdx.x;
    long total8 = 16L * 1024 * 640 / 8;
    if (i8 >= total8) return;
    long e = i8 * 8;
    int c = (int)(e % 640);
    int l = (int)((e / 640) % 1024);
    int b = (int)(e / (640L * 1024));
    float2 st = stat[b];
    short8 v = *(const short8*)(y + e);
    f32x4 f0 = *(const f32x4*)(feats + e);
    f32x4 f1 = *(const f32x4*)(feats + e + 4);
    short8 o;
#pragma unroll
    for (int j = 0; j < 4; ++j) {
        o[j] = f2b(leakyf((b2f(v[j]) - st.x) * st.y) + f0[j]);
        o[j + 4] = f2b(leakyf((b2f(v[j + 4]) - st.x) * st.y) + f1[j]);
    }
    *(short8*)(acat + ((long)b * 1024 + l) * 1280 + 640 + c) = o;
}

// ---------------------------------------------------------------------------
// cp conv3 (N=2): one wave per (b,l), short8-vectorized.
// ---------------------------------------------------------------------------
__global__ void conv3cp_k(const bf16* __restrict__ xp, const bf16* __restrict__ w3,
                          const float* __restrict__ b3, float* __restrict__ sw)
{
    int wid = (int)((blockIdx.x * 256 + threadIdx.x) >> 6);
    int lane = threadIdx.x & 63;
    int b = wid >> 10, l = wid & 1023;
    const short8* xr = (const short8*)(xp + ((long)b * 1026 + l) * 1280);
    const short8* w0 = (const short8*)w3;
    const short8* w1 = (const short8*)(w3 + 3840);
    float a0 = 0.f, a1 = 0.f;
    for (int c = lane; c < 480; c += 64) {
        short8 x = xr[c], u = w0[c], v = w1[c];
#pragma unroll
        for (int j = 0; j < 8; ++j) {
            float xf = b2f(x[j]);
            a0 += xf * b2f(u[j]);
            a1 += xf * b2f(v[j]);
        }
    }
    for (int o = 32; o; o >>= 1) { a0 += __shfl_down(a0, o); a1 += __shfl_down(a1, o); }
    if (lane == 0) {
        sw[b * 2048 + l] = a0 + b3[0];
        sw[b * 2048 + 1024 + l] = a1 + b3[1];
    }
}

// ---------------------------------------------------------------------------
__global__ __launch_bounds__(256) void cp_post_k(const float* __restrict__ sw,
                                                 float* __restrict__ stdb,
                                                 float* __restrict__ wb)
{
    int b = blockIdx.x, tid = threadIdx.x;
    __shared__ float s0[1024], s1[1024], red[256];
    const float* p = sw + b * 2048;
    float s = 0.f, q = 0.f;
    for (int l = tid; l < 1024; l += 256) {
        float v0 = p[l], v1 = p[1024 + l];
        s0[l] = v0; s1[l] = v1;
        s += v0 + v1; q += v0 * v0 + v1 * v1;
    }
    red[tid] = s; __syncthreads();
    for (int o = 128; o; o >>= 1) { if (tid < o) red[tid] += red[tid + o]; __syncthreads(); }
    float mean = red[0] / 2048.f; __syncthreads();
    red[tid] = q; __syncthreads();
    for (int o = 128; o; o >>= 1) { if (tid < o) red[tid] += red[tid + o]; __syncthreads(); }
    float inv = rsqrtf(red[0] / 2048.f - mean * mean + EPS_LN); __syncthreads();
    for (int l = tid; l < 1024; l += 256) {
        s0[l] = leakyf((s0[l] - mean) * inv);
        s1[l] = leakyf((s1[l] - mean) * inv);
    }
    __syncthreads();
    float mx = -1e30f;
    for (int l = tid; l < 1024; l += 256) mx = fmaxf(mx, s0[l]);
    red[tid] = mx; __syncthreads();
    for (int o = 128; o; o >>= 1) { if (tid < o) red[tid] = fmaxf(red[tid], red[tid + o]); __syncthreads(); }
    mx = red[0]; __syncthreads();
    float se = 0.f;
    for (int l = tid; l < 1024; l += 256) { float e = __expf(s0[l] - mx); s0[l] = e; se += e; }
    red[tid] = se; __syncthreads();
    for (int o = 128; o; o >>= 1) { if (tid < o) red[tid] += red[tid + o]; __syncthreads(); }
    float rs = 1.f / red[0]; __syncthreads();
    for (int l = tid; l < 1024; l += 256) stdb[b * 1024 + l] = 102.4f * s0[l] * rs;
    mx = -1e30f;
    for (int l = tid; l < 1024; l += 256) mx = fmaxf(mx, s1[l]);
    red[tid] = mx; __syncthreads();
    for (int o = 128; o; o >>= 1) { if (tid < o) red[tid] = fmaxf(red[tid], red[tid + o]); __syncthreads(); }
    mx = red[0]; __syncthreads();
    se = 0.f;
    for (int l = tid; l < 1024; l += 256) { float e = __expf(s1[l] - mx); s1[l] = e; se += e; }
    red[tid] = se; __syncthreads();
    for (int o = 128; o; o >>= 1) { if (tid < o) red[tid] += red[tid + o]; __syncthreads(); }
    rs = 1.f / red[0]; __syncthreads();
    for (int l = tid; l < 1024; l += 256) wb[b * 1024 + l] = s1[l] * rs;
}

// ---------------------------------------------------------------------------
__global__ __launch_bounds__(256) void pool_k(const float* __restrict__ feats,
                                              const float* __restrict__ stdb,
                                              const float* __restrict__ wb,
                                              bf16* __restrict__ acat)
{
    int i = blockIdx.x, b = blockIdx.y, tid = threadIdx.x;
    float sd = stdb[b * 1024 + i];
    float den = 1e-5f + 2.f * sd * sd;
    float inv = 1.f / den;
    int R = (int)sqrtf(11.5129255f * den) + 1;
    int jlo = max(0, i - R), jhi = min(1023, i + R);
    __shared__ float cj[256];
    float a0 = 0.f, a1 = 0.f, a2 = 0.f;
    const float* fb = feats + (long)b * 1024 * 640;
    for (int j0 = jlo; j0 <= jhi; j0 += 256) {
        int j = j0 + tid;
        float c = 0.f;
        if (j <= jhi) {
            float d = (float)(j - i);
            c = __expf(-d * d * inv) * wb[b * 1024 + j];
        }
        __syncthreads();
        cj[tid] = c;
        __syncthreads();
        int lim = min(256, jhi - j0 + 1);
        for (int t = 0; t < lim; ++t) {
            float cc = cj[t];
            const float* fr = fb + (long)(j0 + t) * 640;
            a0 += cc * fr[tid];
            a1 += cc * fr[tid + 256];
            if (tid < 128) a2 += cc * fr[tid + 512];
        }
    }
    long obase = ((long)b * 1024 + i) * 1280;
    long fbase = ((long)b * 1024 + i) * 640;
    acat[obase + tid] = __float2bfloat16(a0 + feats[fbase + tid]);
    acat[obase + tid + 256] = __float2bfloat16(a1 + feats[fbase + tid + 256]);
    if (tid < 128) acat[obase + tid + 512] = __float2bfloat16(a2 + feats[fbase + tid + 512]);
}

// ---------------------------------------------------------------------------
__global__ void repack_w_k(const float* __restrict__ w, bf16* __restrict__ bt, int CO, int CI)
{
    long idx = (long)blockIdx.x * 256 + threadIdx.x;
    long total = (long)CO * CI * 3;
    if (idx >= total) return;
    int K3 = 3 * CI;
    int o = (int)(idx / K3);
    int k = (int)(idx % K3);
    int t = k / CI, ci = k % CI;
    bt[idx] = __float2bfloat16(w[(long)o * CI * 3 + ci * 3 + t]);
}

__global__ void cast_bf16_k(const float* __restrict__ w, bf16* __restrict__ o, long n)
{
    long idx = (long)blockIdx.x * 256 + threadIdx.x;
    if (idx < n) o[idx] = __float2bfloat16(w[idx]);
}

// ---------------------------------------------------------------------------
extern "C" void kernel_launch(void* const* d_in, const int* in_sizes, int n_in,
                              void* d_out, int out_size, void* d_ws, size_t ws_size,
                              hipStream_t stream)
{
    const float* feats = (const float*)d_in[0];
    const float* cp_w1 = (const float*)d_in[1];
    const float* cp_b1 = (const float*)d_in[2];
    const float* cp_w2 = (const float*)d_in[3];
    const float* cp_b2 = (const float*)d_in[4];
    const float* cp_w3 = (const float*)d_in[5];
    const float* cp_b3 = (const float*)d_in[6];
    const float* cv_w1 = (const float*)d_in[7];
    const float* cv_b1 = (const float*)d_in[8];
    const float* cv_w2 = (const float*)d_in[9];
    const float* cv_b2 = (const float*)d_in[10];
    const float* cv_w3 = (const float*)d_in[11];
    const float* cv_b3 = (const float*)d_in[12];
    const float* mlp_w = (const float*)d_in[13];
    const float* mlp_b = (const float*)d_in[14];
    float* out = (float*)d_out;

    char* ws = (char*)d_ws;
    size_t off = 0;
    auto alloc = [&](size_t bytes) -> char* {
        char* p = ws + off;
        off += (bytes + 255) & ~(size_t)255;
        return p;
    };
    // R1 region: XpadF (21 MB, dead after r1 GEMM) overlaps Acat (42 MB,
    // written only by pool_k / norm_addf, both after r1).
    char* R1 = alloc(16L * 1024 * 1280 * 2);
    bf16* XpadF = (bf16*)R1;
    bf16* Acat = (bf16*)R1;
    bf16* Xp_cp = (bf16*)alloc(16L * 1026 * 1280 * 2);
    bf16* Xp_cv = (bf16*)alloc(16L * 1026 * 1280 * 2);
    bf16* Y0 = (bf16*)alloc(16L * 1024 * 1280 * 2);
    bf16* Y1 = (bf16*)alloc(16L * 1024 * 1280 * 2);
    bf16* Ycv3 = Y0;  // Y0 dead after r2 norm (cp)
    bf16* Bm1 = (bf16*)alloc(2560L * 1920 * 2);
    bf16* Bcp2 = (bf16*)alloc(1280L * 3840 * 2);
    bf16* Bcv2 = (bf16*)alloc(1280L * 3840 * 2);
    bf16* Bcp3 = (bf16*)alloc(2L * 3840 * 2);
    bf16* Bcv3 = (bf16*)alloc(640L * 3840 * 2);
    bf16* Bmlp = (bf16*)alloc(640L * 1280 * 2);
    float* swb = (float*)alloc(16L * 2048 * 4);
    float* stdb = (float*)alloc(16L * 1024 * 4);
    float* wbf = (float*)alloc(16L * 1024 * 4);
    float2* sacc = (float2*)alloc(80L * 8);
    float2* stat = (float2*)alloc(80L * 8);
    (void)ws_size; (void)in_sizes; (void)n_in; (void)out_size;

    const long NF8 = 16L * 1026 * 640 / 8;
    const long N28 = 16L * 1026 * 1280 / 8;
    const long NA8 = 16L * 1024 * 640 / 8;
    const long N1280 = 1024L * 1280, N640 = 1024L * 640;
    const float inv1280 = 1.f / (float)N1280, inv640 = 1.f / (float)N640;

    zero_stats_k<<<1, 128, 0, stream>>>(sacc);
    pack_feats_v_k<<<(NF8 + 255) / 256, 256, 0, stream>>>(feats, XpadF, 640);
    repack_w_k<<<(1280L * 640 * 3 + 255) / 256, 256, 0, stream>>>(cp_w1, Bm1, 1280, 640);
    repack_w_k<<<(1280L * 640 * 3 + 255) / 256, 256, 0, stream>>>(cv_w1, Bm1 + 1280L * 1920, 1280, 640);
    repack_w_k<<<(1280L * 1280 * 3 + 255) / 256, 256, 0, stream>>>(cp_w2, Bcp2, 1280, 1280);
    repack_w_k<<<(1280L * 1280 * 3 + 255) / 256, 256, 0, stream>>>(cv_w2, Bcv2, 1280, 1280);
    repack_w_k<<<(2L * 1280 * 3 + 255) / 256, 256, 0, stream>>>(cp_w3, Bcp3, 2, 1280);
    repack_w_k<<<(640L * 1280 * 3 + 255) / 256, 256, 0, stream>>>(cv_w3, Bcv3, 640, 1280);
    cast_bf16_k<<<(640L * 1280 + 255) / 256, 256, 0, stream>>>(mlp_w, Bmlp, 640L * 1280);

    // ---- round 1: cp1 + cv1 merged (2560 wg = 5 x 512, no tail round) ----
    gemm_dual<0><<<2560, 256, 0, stream>>>(
        XpadF, XpadF, 1026L * 640, 640, Bm1, Bm1 + 1280L * 1920,
        cp_b1, cv_b1, Y0, Y1, N1280, 1280, 1920, 10, 8, 1280,
        sacc, sacc + 16);
    fin_k<<<1, 64, 0, stream>>>(sacc, stat, inv1280, 32);
    norm_pack_v_k<<<(N28 + 255) / 256, 256, 0, stream>>>(Y0, stat, Xp_cp, 1280);
    norm_pack_v_k<<<(N28 + 255) / 256, 256, 0, stream>>>(Y1, stat + 16, Xp_cv, 1280);

    // ---- round 2: cp2 + cv2 merged ----
    gemm_dual<0><<<2560, 256, 0, stream>>>(
        Xp_cp, Xp_cv, 1026L * 1280, 1280, Bcp2, Bcv2,
        cp_b2, cv_b2, Y0, Y1, N1280, 1280, 3840, 10, 8, 1280,
        sacc + 32, sacc + 48);
    fin_k<<<1, 64, 0, stream>>>(sacc + 32, stat + 32, inv1280, 32);
    norm_pack_v_k<<<(N28 + 255) / 256, 256, 0, stream>>>(Y0, stat + 32, Xp_cp, 1280);
    norm_pack_v_k<<<(N28 + 255) / 256, 256, 0, stream>>>(Y1, stat + 48, Xp_cv, 1280);

    // ---- cp tail: conv3 -> softmaxes -> pooling ----
    conv3cp_k<<<4096, 256, 0, stream>>>(Xp_cp, Bcp3, cp_b3, swb);
    cp_post_k<<<16, 256, 0, stream>>>(swb, stdb, wbf);
    pool_k<<<dim3(1024, 16), 256, 0, stream>>>(feats, stdb, wbf, Acat);

    // ---- cv3 ----
    gemm_dual<0><<<640, 256, 0, stream>>>(
        Xp_cv, Xp_cv, 1026L * 1280, 1280, Bcv3, Bcv3,
        cv_b3, cv_b3, Ycv3, Ycv3, N640, 640, 3840, 5, 8, 640,
        sacc + 64, sacc + 64);
    fin_k<<<1, 64, 0, stream>>>(sacc + 64, stat + 64, inv640, 16);
    norm_addf_v_k<<<(NA8 + 255) / 256, 256, 0, stream>>>(Ycv3, stat + 64, feats, Acat);

    // ---- MLP ----
    gemm_dual<1><<<640, 256, 0, stream>>>(
        Acat, Acat, N1280, 1280, Bmlp, Bmlp,
        mlp_b, mlp_b, out, out, N640, 640, 1280, 5, 8, 640,
        nullptr, nullptr);
}

// Round 7
// 738.125 us; speedup vs baseline: 1.2785x; 1.0666x over previous
//
#include <hip/hip_runtime.h>
#include <hip/hip_bf16.h>
#include <math.h>

#define SLOPE 0.01f
#define EPS_LN 1e-5f

typedef __hip_bfloat16 bf16;
typedef __attribute__((ext_vector_type(8))) short short8;
typedef __attribute__((ext_vector_type(4))) float f32x4;

__device__ __forceinline__ float leakyf(float x) { return x < 0.f ? SLOPE * x : x; }

__device__ __forceinline__ float b2f(short s) {
    unsigned u = ((unsigned)(unsigned short)s) << 16;
    return __builtin_bit_cast(float, u);
}
__device__ __forceinline__ short f2b(float f) {
    __hip_bfloat16 h = __float2bfloat16(f);
    return *(short*)&h;
}

__device__ __forceinline__ void gload_lds16(const void* g, void* l) {
    __builtin_amdgcn_global_load_lds(
        (const __attribute__((address_space(1))) void*)g,
        (__attribute__((address_space(3))) void*)l, 16, 0, 0);
}

// ---------------------------------------------------------------------------
// 2-phase 128x128 GEMM (proven 920-1040 TF) with DUAL-problem branch.
// T2 swizzle (pre-swizzled global src + XOR ds_read), T1 XCD-chunked bids.
// EPI 0: out bf16 + per-batch sum/sumsq atomics; EPI 1: f32 out, bias+leaky.
// ---------------------------------------------------------------------------
template <int EPI>
__global__ __launch_bounds__(256, 2) void gemm_dual(
    const bf16* __restrict__ A0, const bf16* __restrict__ A1, long sA, int ldA,
    const bf16* __restrict__ Bt0, const bf16* __restrict__ Bt1,
    const float* __restrict__ bias0, const float* __restrict__ bias1,
    void* __restrict__ Out0, void* __restrict__ Out1, long sO, int ldO, int K,
    int gx, int gy, int halfwg,
    float2* __restrict__ stats0, float2* __restrict__ stats1)
{
    __shared__ bf16 As[128][64];
    __shared__ bf16 Bs[128][64];

    const int nwg = gridDim.x;
    const int wid = (blockIdx.x & 7) * (nwg >> 3) + (blockIdx.x >> 3);
    const int branch = wid >= halfwg;
    const int w = wid - branch * halfwg;
    const int bx = w % gx;                 // bx-inner: A-panel L2-resident
    const int by = (w / gx) % gy;
    const int bz = w / (gx * gy);

    const bf16* A = branch ? A1 : A0;
    const bf16* Bt = branch ? Bt1 : Bt0;
    const float* bias = branch ? bias1 : bias0;
    void* Outv = branch ? Out1 : Out0;
    float2* stats = branch ? stats1 : stats0;

    const bf16* Ab = A + (long)bz * sA + (long)by * 128 * ldA;
    const bf16* Bb = Bt + (long)bx * 128 * K;
    const int tid = threadIdx.x;
    const int wave = tid >> 6, lane = tid & 63;
    const int moff = (wave >> 1) * 64, noff = (wave & 1) * 64;
    const int r16 = lane & 15, g4 = lane >> 4;
    const int r7 = r16 & 7;

    f32x4 acc[4][4];
#pragma unroll
    for (int i = 0; i < 4; ++i)
#pragma unroll
        for (int j = 0; j < 4; ++j)
            acc[i][j] = (f32x4){0.f, 0.f, 0.f, 0.f};

    for (int k0 = 0; k0 < K; k0 += 64) {
        __syncthreads();
#pragma unroll
        for (int i = 0; i < 4; ++i) {
            int chunk = i * 256 + tid;
            int row = chunk >> 3;
            int kc = (chunk ^ (chunk >> 3)) & 7;
            gload_lds16(Ab + (long)row * ldA + (k0 + kc * 8),
                        (char*)(&As[0][0]) + (i * 256 + wave * 64) * 16);
        }
#pragma unroll
        for (int i = 0; i < 4; ++i) {
            int chunk = i * 256 + tid;
            int row = chunk >> 3;
            int kc = (chunk ^ (chunk >> 3)) & 7;
            gload_lds16(Bb + (long)row * K + (k0 + kc * 8),
                        (char*)(&Bs[0][0]) + (i * 256 + wave * 64) * 16);
        }
        __syncthreads();
#pragma unroll
        for (int kk = 0; kk < 2; ++kk) {
            short8 af[4], bfr[4];
#pragma unroll
            for (int mi = 0; mi < 4; ++mi)
                af[mi] = *(const short8*)&As[moff + mi * 16 + r16][((kk * 4 + g4) ^ r7) * 8];
#pragma unroll
            for (int ni = 0; ni < 4; ++ni)
                bfr[ni] = *(const short8*)&Bs[noff + ni * 16 + r16][((kk * 4 + g4) ^ r7) * 8];
#pragma unroll
            for (int mi = 0; mi < 4; ++mi)
#pragma unroll
                for (int ni = 0; ni < 4; ++ni)
                    acc[mi][ni] = __builtin_amdgcn_mfma_f32_16x16x32_bf16(
                        af[mi], bfr[ni], acc[mi][ni], 0, 0, 0);
        }
    }

    float s = 0.f, q = 0.f;
#pragma unroll
    for (int mi = 0; mi < 4; ++mi) {
#pragma unroll
        for (int ni = 0; ni < 4; ++ni) {
            int col = bx * 128 + noff + ni * 16 + r16;
            float bv = bias[col];
#pragma unroll
            for (int r = 0; r < 4; ++r) {
                int row = by * 128 + moff + mi * 16 + g4 * 4 + r;
                float v = acc[mi][ni][r] + bv;
                if (EPI == 1) {
                    ((float*)Outv)[(long)bz * sO + (long)row * ldO + col] = leakyf(v);
                } else {
                    ((bf16*)Outv)[(long)bz * sO + (long)row * ldO + col] = __float2bfloat16(v);
                    s += v; q += v * v;
                }
            }
        }
    }
    if (EPI == 0) {
        __syncthreads();
        float* red = (float*)&As[0][0];
        float* red2 = red + 256;
        red[tid] = s; red2[tid] = q;
        __syncthreads();
        for (int o = 128; o; o >>= 1) {
            if (tid < o) { red[tid] += red[tid + o]; red2[tid] += red2[tid + o]; }
            __syncthreads();
        }
        if (tid == 0) {
            atomicAdd(&stats[bz].x, red[0]);
            atomicAdd(&stats[bz].y, red2[0]);
        }
    }
}

// ---------------------------------------------------------------------------
// Mega-prep: sacc zero + feats pack (8-elem chunks) + all weight repacks,
// flat-index range dispatch. Replaces 9 launches.
// ---------------------------------------------------------------------------
__device__ __forceinline__ void repack1(const float* __restrict__ w,
                                        bf16* __restrict__ bt, long idx, int CI)
{
    int K3 = 3 * CI;
    int o = (int)(idx / K3);
    int k = (int)(idx % K3);
    int t = k / CI, ci = k % CI;
    bt[idx] = __float2bfloat16(w[(long)o * CI * 3 + ci * 3 + t]);
}

__global__ void prep_k(const float* __restrict__ feats,
                       const float* __restrict__ cp_w1, const float* __restrict__ cv_w1,
                       const float* __restrict__ cp_w2, const float* __restrict__ cv_w2,
                       const float* __restrict__ cp_w3, const float* __restrict__ cv_w3,
                       const float* __restrict__ mlp_w,
                       bf16* __restrict__ xp,
                       bf16* __restrict__ Bm1a, bf16* __restrict__ Bm1b,
                       bf16* __restrict__ Bcp2, bf16* __restrict__ Bcv2,
                       bf16* __restrict__ Bcp3, bf16* __restrict__ Bcv3,
                       bf16* __restrict__ Bmlp, float2* __restrict__ sacc)
{
    long idx = (long)blockIdx.x * 256 + threadIdx.x;
    // [0] zero the stats accumulators
    if (idx < 80) { sacc[idx] = make_float2(0.f, 0.f); return; }
    idx -= 80;
    // [1] feats f32 [B,1024,640] -> padded bf16 [B,1026,640], 8 elems/thread
    const long NPACK8 = 16L * 1026 * 640 / 8;
    if (idx < NPACK8) {
        long e = idx * 8;
        int c = (int)(e % 640);
        long t = e / 640;
        int r = (int)(t % 1026);
        int b = (int)(t / 1026);
        short8 o;
        if (r == 0 || r == 1025) {
#pragma unroll
            for (int j = 0; j < 8; ++j) o[j] = 0;
        } else {
            const float* src = feats + ((long)b * 1024 + (r - 1)) * 640 + c;
            f32x4 v0 = *(const f32x4*)src;
            f32x4 v1 = *(const f32x4*)(src + 4);
#pragma unroll
            for (int j = 0; j < 4; ++j) { o[j] = f2b(v0[j]); o[j + 4] = f2b(v1[j]); }
        }
        *(short8*)(xp + e) = o;
        return;
    }
    idx -= NPACK8;
    const long W1 = 1280L * 640 * 3;   // 2,457,600
    const long W2 = 1280L * 1280 * 3;  // 4,915,200
    if (idx < W1) { repack1(cp_w1, Bm1a, idx, 640); return; }
    idx -= W1;
    if (idx < W1) { repack1(cv_w1, Bm1b, idx, 640); return; }
    idx -= W1;
    if (idx < W2) { repack1(cp_w2, Bcp2, idx, 1280); return; }
    idx -= W2;
    if (idx < W2) { repack1(cv_w2, Bcv2, idx, 1280); return; }
    idx -= W2;
    if (idx < 2L * 1280 * 3) { repack1(cp_w3, Bcp3, idx, 1280); return; }
    idx -= 2L * 1280 * 3;
    const long W3 = 640L * 1280 * 3;
    if (idx < W3) { repack1(cv_w3, Bcv3, idx, 1280); return; }
    idx -= W3;
    if (idx < 640L * 1280) { Bmlp[idx] = __float2bfloat16(mlp_w[idx]); return; }
}

// ---------------------------------------------------------------------------
// Merged dual norm+pack with INLINE stat finalize (fin_k folded in):
// prob = blockIdx.y selects (Y0->X0, sacc[sbase+b]) or (Y1->X1, sacc[sbase+16+b]).
// ---------------------------------------------------------------------------
__global__ void norm_pack2_k(const bf16* __restrict__ y0, const bf16* __restrict__ y1,
                             bf16* __restrict__ x0, bf16* __restrict__ x1,
                             const float2* __restrict__ sacc, int sbase, float invN)
{
    const int prob = blockIdx.y;
    const bf16* y = prob ? y1 : y0;
    bf16* xp = prob ? x1 : x0;
    long i8 = (long)blockIdx.x * 256 + threadIdx.x;
    const long total8 = 16L * 1026 * 1280 / 8;
    if (i8 >= total8) return;
    long e = i8 * 8;
    int c = (int)(e % 1280);
    long t = e / 1280;
    int r = (int)(t % 1026);
    int b = (int)(t / 1026);
    short8 o;
    if (r == 0 || r == 1025) {
#pragma unroll
        for (int j = 0; j < 8; ++j) o[j] = 0;
    } else {
        float2 a = sacc[sbase + prob * 16 + b];
        float m = a.x * invN;
        float rstd = rsqrtf(a.y * invN - m * m + EPS_LN);
        short8 v = *(const short8*)(y + ((long)b * 1024 + (r - 1)) * 1280 + c);
#pragma unroll
        for (int j = 0; j < 8; ++j)
            o[j] = f2b(leakyf((b2f(v[j]) - m) * rstd));
    }
    *(short8*)(xp + e) = o;
}

// cv3: Y bf16 -> leaky(LN) + feats -> Acat[:, :, 640:1280], inline stat.
__global__ void norm_addf_v_k(const bf16* __restrict__ y, const float2* __restrict__ sacc,
                              const float* __restrict__ feats, bf16* __restrict__ acat,
                              float invN)
{
    long i8 = (long)blockIdx.x * 256 + threadIdx.x;
    long total8 = 16L * 1024 * 640 / 8;
    if (i8 >= total8) return;
    long e = i8 * 8;
    int c = (int)(e % 640);
    int l = (int)((e / 640) % 1024);
    int b = (int)(e / (640L * 1024));
    float2 a = sacc[64 + b];
    float m = a.x * invN;
    float rstd = rsqrtf(a.y * invN - m * m + EPS_LN);
    short8 v = *(const short8*)(y + e);
    f32x4 f0 = *(const f32x4*)(feats + e);
    f32x4 f1 = *(const f32x4*)(feats + e + 4);
    short8 o;
#pragma unroll
    for (int j = 0; j < 4; ++j) {
        o[j] = f2b(leakyf((b2f(v[j]) - m) * rstd) + f0[j]);
        o[j + 4] = f2b(leakyf((b2f(v[j + 4]) - m) * rstd) + f1[j]);
    }
    *(short8*)(acat + ((long)b * 1024 + l) * 1280 + 640 + c) = o;
}

// ---------------------------------------------------------------------------
// cp conv3 (N=2): one wave per (b,l), short8-vectorized.
// ---------------------------------------------------------------------------
__global__ void conv3cp_k(const bf16* __restrict__ xp, const bf16* __restrict__ w3,
                          const float* __restrict__ b3, float* __restrict__ sw)
{
    int wid = (int)((blockIdx.x * 256 + threadIdx.x) >> 6);
    int lane = threadIdx.x & 63;
    int b = wid >> 10, l = wid & 1023;
    const short8* xr = (const short8*)(xp + ((long)b * 1026 + l) * 1280);
    const short8* w0 = (const short8*)w3;
    const short8* w1 = (const short8*)(w3 + 3840);
    float a0 = 0.f, a1 = 0.f;
    for (int c = lane; c < 480; c += 64) {
        short8 x = xr[c], u = w0[c], v = w1[c];
#pragma unroll
        for (int j = 0; j < 8; ++j) {
            float xf = b2f(x[j]);
            a0 += xf * b2f(u[j]);
            a1 += xf * b2f(v[j]);
        }
    }
    for (int o = 32; o; o >>= 1) { a0 += __shfl_down(a0, o); a1 += __shfl_down(a1, o); }
    if (lane == 0) {
        sw[b * 2048 + l] = a0 + b3[0];
        sw[b * 2048 + 1024 + l] = a1 + b3[1];
    }
}

// ---------------------------------------------------------------------------
__global__ __launch_bounds__(256) void cp_post_k(const float* __restrict__ sw,
                                                 float* __restrict__ stdb,
                                                 float* __restrict__ wb)
{
    int b = blockIdx.x, tid = threadIdx.x;
    __shared__ float s0[1024], s1[1024], red[256];
    const float* p = sw + b * 2048;
    float s = 0.f, q = 0.f;
    for (int l = tid; l < 1024; l += 256) {
        float v0 = p[l], v1 = p[1024 + l];
        s0[l] = v0; s1[l] = v1;
        s += v0 + v1; q += v0 * v0 + v1 * v1;
    }
    red[tid] = s; __syncthreads();
    for (int o = 128; o; o >>= 1) { if (tid < o) red[tid] += red[tid + o]; __syncthreads(); }
    float mean = red[0] / 2048.f; __syncthreads();
    red[tid] = q; __syncthreads();
    for (int o = 128; o; o >>= 1) { if (tid < o) red[tid] += red[tid + o]; __syncthreads(); }
    float inv = rsqrtf(red[0] / 2048.f - mean * mean + EPS_LN); __syncthreads();
    for (int l = tid; l < 1024; l += 256) {
        s0[l] = leakyf((s0[l] - mean) * inv);
        s1[l] = leakyf((s1[l] - mean) * inv);
    }
    __syncthreads();
    float mx = -1e30f;
    for (int l = tid; l < 1024; l += 256) mx = fmaxf(mx, s0[l]);
    red[tid] = mx; __syncthreads();
    for (int o = 128; o; o >>= 1) { if (tid < o) red[tid] = fmaxf(red[tid], red[tid + o]); __syncthreads(); }
    mx = red[0]; __syncthreads();
    float se = 0.f;
    for (int l = tid; l < 1024; l += 256) { float e = __expf(s0[l] - mx); s0[l] = e; se += e; }
    red[tid] = se; __syncthreads();
    for (int o = 128; o; o >>= 1) { if (tid < o) red[tid] += red[tid + o]; __syncthreads(); }
    float rs = 1.f / red[0]; __syncthreads();
    for (int l = tid; l < 1024; l += 256) stdb[b * 1024 + l] = 102.4f * s0[l] * rs;
    mx = -1e30f;
    for (int l = tid; l < 1024; l += 256) mx = fmaxf(mx, s1[l]);
    red[tid] = mx; __syncthreads();
    for (int o = 128; o; o >>= 1) { if (tid < o) red[tid] = fmaxf(red[tid], red[tid + o]); __syncthreads(); }
    mx = red[0]; __syncthreads();
    se = 0.f;
    for (int l = tid; l < 1024; l += 256) { float e = __expf(s1[l] - mx); s1[l] = e; se += e; }
    red[tid] = se; __syncthreads();
    for (int o = 128; o; o >>= 1) { if (tid < o) red[tid] += red[tid + o]; __syncthreads(); }
    rs = 1.f / red[0]; __syncthreads();
    for (int l = tid; l < 1024; l += 256) wb[b * 1024 + l] = s1[l] * rs;
}

// ---------------------------------------------------------------------------
__global__ __launch_bounds__(256) void pool_k(const float* __restrict__ feats,
                                              const float* __restrict__ stdb,
                                              const float* __restrict__ wb,
                                              bf16* __restrict__ acat)
{
    int i = blockIdx.x, b = blockIdx.y, tid = threadIdx.x;
    float sd = stdb[b * 1024 + i];
    float den = 1e-5f + 2.f * sd * sd;
    float inv = 1.f / den;
    int R = (int)sqrtf(11.5129255f * den) + 1;
    int jlo = max(0, i - R), jhi = min(1023, i + R);
    __shared__ float cj[256];
    float a0 = 0.f, a1 = 0.f, a2 = 0.f;
    const float* fb = feats + (long)b * 1024 * 640;
    for (int j0 = jlo; j0 <= jhi; j0 += 256) {
        int j = j0 + tid;
        float c = 0.f;
        if (j <= jhi) {
            float d = (float)(j - i);
            c = __expf(-d * d * inv) * wb[b * 1024 + j];
        }
        __syncthreads();
        cj[tid] = c;
        __syncthreads();
        int lim = min(256, jhi - j0 + 1);
        for (int t = 0; t < lim; ++t) {
            float cc = cj[t];
            const float* fr = fb + (long)(j0 + t) * 640;
            a0 += cc * fr[tid];
            a1 += cc * fr[tid + 256];
            if (tid < 128) a2 += cc * fr[tid + 512];
        }
    }
    long obase = ((long)b * 1024 + i) * 1280;
    long fbase = ((long)b * 1024 + i) * 640;
    acat[obase + tid] = __float2bfloat16(a0 + feats[fbase + tid]);
    acat[obase + tid + 256] = __float2bfloat16(a1 + feats[fbase + tid + 256]);
    if (tid < 128) acat[obase + tid + 512] = __float2bfloat16(a2 + feats[fbase + tid + 512]);
}

// ---------------------------------------------------------------------------
extern "C" void kernel_launch(void* const* d_in, const int* in_sizes, int n_in,
                              void* d_out, int out_size, void* d_ws, size_t ws_size,
                              hipStream_t stream)
{
    const float* feats = (const float*)d_in[0];
    const float* cp_w1 = (const float*)d_in[1];
    const float* cp_b1 = (const float*)d_in[2];
    const float* cp_w2 = (const float*)d_in[3];
    const float* cp_b2 = (const float*)d_in[4];
    const float* cp_w3 = (const float*)d_in[5];
    const float* cp_b3 = (const float*)d_in[6];
    const float* cv_w1 = (const float*)d_in[7];
    const float* cv_b1 = (const float*)d_in[8];
    const float* cv_w2 = (const float*)d_in[9];
    const float* cv_b2 = (const float*)d_in[10];
    const float* cv_w3 = (const float*)d_in[11];
    const float* cv_b3 = (const float*)d_in[12];
    const float* mlp_w = (const float*)d_in[13];
    const float* mlp_b = (const float*)d_in[14];
    float* out = (float*)d_out;

    char* ws = (char*)d_ws;
    size_t off = 0;
    auto alloc = [&](size_t bytes) -> char* {
        char* p = ws + off;
        off += (bytes + 255) & ~(size_t)255;
        return p;
    };
    // R1 region: XpadF (21 MB, dead after r1 GEMM) overlaps Acat (42 MB,
    // written only by pool_k / norm_addf, both after r1).
    char* R1 = alloc(16L * 1024 * 1280 * 2);
    bf16* XpadF = (bf16*)R1;
    bf16* Acat = (bf16*)R1;
    bf16* Xp_cp = (bf16*)alloc(16L * 1026 * 1280 * 2);
    bf16* Xp_cv = (bf16*)alloc(16L * 1026 * 1280 * 2);
    bf16* Y0 = (bf16*)alloc(16L * 1024 * 1280 * 2);
    bf16* Y1 = (bf16*)alloc(16L * 1024 * 1280 * 2);
    bf16* Ycv3 = Y0;  // Y0 dead after r2 norm (cp)
    bf16* Bm1 = (bf16*)alloc(2560L * 1920 * 2);
    bf16* Bcp2 = (bf16*)alloc(1280L * 3840 * 2);
    bf16* Bcv2 = (bf16*)alloc(1280L * 3840 * 2);
    bf16* Bcp3 = (bf16*)alloc(2L * 3840 * 2);
    bf16* Bcv3 = (bf16*)alloc(640L * 3840 * 2);
    bf16* Bmlp = (bf16*)alloc(640L * 1280 * 2);
    float* swb = (float*)alloc(16L * 2048 * 4);
    float* stdb = (float*)alloc(16L * 1024 * 4);
    float* wbf = (float*)alloc(16L * 1024 * 4);
    float2* sacc = (float2*)alloc(80L * 8);
    (void)ws_size; (void)in_sizes; (void)n_in; (void)out_size;

    const long N28 = 16L * 1026 * 1280 / 8;
    const long NA8 = 16L * 1024 * 640 / 8;
    const long N1280 = 1024L * 1280, N640 = 1024L * 640;
    const float inv1280 = 1.f / (float)N1280, inv640 = 1.f / (float)N640;

    // ---- prep: sacc zero + feats pack + all weight repacks (1 launch) ----
    const long NPREP = 80 + 16L * 1026 * 640 / 8 + 2 * (1280L * 640 * 3)
                     + 2 * (1280L * 1280 * 3) + 2L * 1280 * 3
                     + 640L * 1280 * 3 + 640L * 1280;
    prep_k<<<(int)((NPREP + 255) / 256), 256, 0, stream>>>(
        feats, cp_w1, cv_w1, cp_w2, cv_w2, cp_w3, cv_w3, mlp_w,
        XpadF, Bm1, Bm1 + 1280L * 1920, Bcp2, Bcv2, Bcp3, Bcv3, Bmlp, sacc);

    // ---- round 1: cp1 + cv1 merged (2560 wg) ----
    gemm_dual<0><<<2560, 256, 0, stream>>>(
        XpadF, XpadF, 1026L * 640, 640, Bm1, Bm1 + 1280L * 1920,
        cp_b1, cv_b1, Y0, Y1, N1280, 1280, 1920, 10, 8, 1280,
        sacc, sacc + 16);
    norm_pack2_k<<<dim3((N28 + 255) / 256, 2), 256, 0, stream>>>(
        Y0, Y1, Xp_cp, Xp_cv, sacc, 0, inv1280);

    // ---- round 2: cp2 + cv2 merged ----
    gemm_dual<0><<<2560, 256, 0, stream>>>(
        Xp_cp, Xp_cv, 1026L * 1280, 1280, Bcp2, Bcv2,
        cp_b2, cv_b2, Y0, Y1, N1280, 1280, 3840, 10, 8, 1280,
        sacc + 32, sacc + 48);
    norm_pack2_k<<<dim3((N28 + 255) / 256, 2), 256, 0, stream>>>(
        Y0, Y1, Xp_cp, Xp_cv, sacc, 32, inv1280);

    // ---- cp tail: conv3 -> softmaxes -> pooling ----
    conv3cp_k<<<4096, 256, 0, stream>>>(Xp_cp, Bcp3, cp_b3, swb);
    cp_post_k<<<16, 256, 0, stream>>>(swb, stdb, wbf);
    pool_k<<<dim3(1024, 16), 256, 0, stream>>>(feats, stdb, wbf, Acat);

    // ---- cv3 ----
    gemm_dual<0><<<640, 256, 0, stream>>>(
        Xp_cv, Xp_cv, 1026L * 1280, 1280, Bcv3, Bcv3,
        cv_b3, cv_b3, Ycv3, Ycv3, N640, 640, 3840, 5, 8, 640,
        sacc + 64, sacc + 64);
    norm_addf_v_k<<<(NA8 + 255) / 256, 256, 0, stream>>>(Ycv3, sacc, feats, Acat, inv640);

    // ---- MLP ----
    gemm_dual<1><<<640, 256, 0, stream>>>(
        Acat, Acat, N1280, 1280, Bmlp, Bmlp,
        mlp_b, mlp_b, out, out, N640, 640, 1280, 5, 8, 640,
        nullptr, nullptr);
}

// Round 8
// 720.858 us; speedup vs baseline: 1.3091x; 1.0240x over previous
//
#include <hip/hip_runtime.h>
#include <hip/hip_bf16.h>
#include <math.h>

#define SLOPE 0.01f
#define EPS_LN 1e-5f

typedef __hip_bfloat16 bf16;
typedef __attribute__((ext_vector_type(8))) short short8;
typedef __attribute__((ext_vector_type(4))) float f32x4;

__device__ __forceinline__ float leakyf(float x) { return x < 0.f ? SLOPE * x : x; }

__device__ __forceinline__ float b2f(short s) {
    unsigned u = ((unsigned)(unsigned short)s) << 16;
    return __builtin_bit_cast(float, u);
}
__device__ __forceinline__ short f2b(float f) {
    __hip_bfloat16 h = __float2bfloat16(f);
    return *(short*)&h;
}

__device__ __forceinline__ void gload_lds16(const void* g, void* l) {
    __builtin_amdgcn_global_load_lds(
        (const __attribute__((address_space(1))) void*)g,
        (__attribute__((address_space(3))) void*)l, 16, 0, 0);
}

// ---------------------------------------------------------------------------
// 2-phase 128x128 GEMM (proven 985-1040 TF) with DUAL-problem branch.
// T2 swizzle (pre-swizzled global src + XOR ds_read), T1 XCD-chunked bids.
// EPI 0: out bf16 + per-batch sum/sumsq atomics; EPI 1: f32 out, bias+leaky.
// ---------------------------------------------------------------------------
template <int EPI>
__global__ __launch_bounds__(256, 2) void gemm_dual(
    const bf16* __restrict__ A0, const bf16* __restrict__ A1, long sA, int ldA,
    const bf16* __restrict__ Bt0, const bf16* __restrict__ Bt1,
    const float* __restrict__ bias0, const float* __restrict__ bias1,
    void* __restrict__ Out0, void* __restrict__ Out1, long sO, int ldO, int K,
    int gx, int gy, int halfwg,
    float2* __restrict__ stats0, float2* __restrict__ stats1)
{
    __shared__ bf16 As[128][64];
    __shared__ bf16 Bs[128][64];

    const int nwg = gridDim.x;
    const int wid = (blockIdx.x & 7) * (nwg >> 3) + (blockIdx.x >> 3);
    const int branch = wid >= halfwg;
    const int w = wid - branch * halfwg;
    const int bx = w % gx;                 // bx-inner: A-panel L2-resident
    const int by = (w / gx) % gy;
    const int bz = w / (gx * gy);

    const bf16* A = branch ? A1 : A0;
    const bf16* Bt = branch ? Bt1 : Bt0;
    const float* bias = branch ? bias1 : bias0;
    void* Outv = branch ? Out1 : Out0;
    float2* stats = branch ? stats1 : stats0;

    const bf16* Ab = A + (long)bz * sA + (long)by * 128 * ldA;
    const bf16* Bb = Bt + (long)bx * 128 * K;
    const int tid = threadIdx.x;
    const int wave = tid >> 6, lane = tid & 63;
    const int moff = (wave >> 1) * 64, noff = (wave & 1) * 64;
    const int r16 = lane & 15, g4 = lane >> 4;
    const int r7 = r16 & 7;

    f32x4 acc[4][4];
#pragma unroll
    for (int i = 0; i < 4; ++i)
#pragma unroll
        for (int j = 0; j < 4; ++j)
            acc[i][j] = (f32x4){0.f, 0.f, 0.f, 0.f};

    for (int k0 = 0; k0 < K; k0 += 64) {
        __syncthreads();
#pragma unroll
        for (int i = 0; i < 4; ++i) {
            int chunk = i * 256 + tid;
            int row = chunk >> 3;
            int kc = (chunk ^ (chunk >> 3)) & 7;
            gload_lds16(Ab + (long)row * ldA + (k0 + kc * 8),
                        (char*)(&As[0][0]) + (i * 256 + wave * 64) * 16);
        }
#pragma unroll
        for (int i = 0; i < 4; ++i) {
            int chunk = i * 256 + tid;
            int row = chunk >> 3;
            int kc = (chunk ^ (chunk >> 3)) & 7;
            gload_lds16(Bb + (long)row * K + (k0 + kc * 8),
                        (char*)(&Bs[0][0]) + (i * 256 + wave * 64) * 16);
        }
        __syncthreads();
#pragma unroll
        for (int kk = 0; kk < 2; ++kk) {
            short8 af[4], bfr[4];
#pragma unroll
            for (int mi = 0; mi < 4; ++mi)
                af[mi] = *(const short8*)&As[moff + mi * 16 + r16][((kk * 4 + g4) ^ r7) * 8];
#pragma unroll
            for (int ni = 0; ni < 4; ++ni)
                bfr[ni] = *(const short8*)&Bs[noff + ni * 16 + r16][((kk * 4 + g4) ^ r7) * 8];
#pragma unroll
            for (int mi = 0; mi < 4; ++mi)
#pragma unroll
                for (int ni = 0; ni < 4; ++ni)
                    acc[mi][ni] = __builtin_amdgcn_mfma_f32_16x16x32_bf16(
                        af[mi], bfr[ni], acc[mi][ni], 0, 0, 0);
        }
    }

    float s = 0.f, q = 0.f;
#pragma unroll
    for (int mi = 0; mi < 4; ++mi) {
#pragma unroll
        for (int ni = 0; ni < 4; ++ni) {
            int col = bx * 128 + noff + ni * 16 + r16;
            float bv = bias[col];
#pragma unroll
            for (int r = 0; r < 4; ++r) {
                int row = by * 128 + moff + mi * 16 + g4 * 4 + r;
                float v = acc[mi][ni][r] + bv;
                if (EPI == 1) {
                    ((float*)Outv)[(long)bz * sO + (long)row * ldO + col] = leakyf(v);
                } else {
                    ((bf16*)Outv)[(long)bz * sO + (long)row * ldO + col] = __float2bfloat16(v);
                    s += v; q += v * v;
                }
            }
        }
    }
    if (EPI == 0) {
        __syncthreads();
        float* red = (float*)&As[0][0];
        float* red2 = red + 256;
        red[tid] = s; red2[tid] = q;
        __syncthreads();
        for (int o = 128; o; o >>= 1) {
            if (tid < o) { red[tid] += red[tid + o]; red2[tid] += red2[tid + o]; }
            __syncthreads();
        }
        if (tid == 0) {
            atomicAdd(&stats[bz].x, red[0]);
            atomicAdd(&stats[bz].y, red2[0]);
        }
    }
}

// ---------------------------------------------------------------------------
// Fused cv3-GEMM + pooling: raw blockIdx < 640 -> cv3 GEMM path (byte-copy of
// gemm_dual<0> with cv3 params; own XCD swizzle over 640); rest -> pool4
// (4 query rows per block: adjacent windows overlap, 4x feats-row reuse).
// Raw blockIdx round-robins XCDs, so GEMM blocks spread evenly and pool
// blocks fill idle slots + GEMM stall shadows.
// ---------------------------------------------------------------------------
__global__ __launch_bounds__(256, 2) void cv3_pool_k(
    const bf16* __restrict__ Axp, const bf16* __restrict__ Bt,
    const float* __restrict__ bias, bf16* __restrict__ Y,
    float2* __restrict__ stats,
    const float* __restrict__ feats, const float* __restrict__ stdb,
    const float* __restrict__ wb, bf16* __restrict__ acat)
{
    __shared__ bf16 As[128][64];
    __shared__ bf16 Bs[128][64];
    __shared__ float cj4[4][256];

    const int tid = threadIdx.x;
    if (blockIdx.x < 640) {
        // ---------------- cv3 GEMM (K=3840, gx=5, gy=8, 16 batches) --------
        const int wid = (blockIdx.x & 7) * 80 + (blockIdx.x >> 3);
        const int bx = wid % 5;
        const int by = (wid / 5) % 8;
        const int bz = wid / 40;
        const int K = 3840;
        const bf16* Ab = Axp + ((long)bz * 1026 + (long)by * 128) * 1280;
        const bf16* Bb = Bt + (long)bx * 128 * K;
        const int wave = tid >> 6, lane = tid & 63;
        const int moff = (wave >> 1) * 64, noff = (wave & 1) * 64;
        const int r16 = lane & 15, g4 = lane >> 4;
        const int r7 = r16 & 7;

        f32x4 acc[4][4];
#pragma unroll
        for (int i = 0; i < 4; ++i)
#pragma unroll
            for (int j = 0; j < 4; ++j)
                acc[i][j] = (f32x4){0.f, 0.f, 0.f, 0.f};

        for (int k0 = 0; k0 < K; k0 += 64) {
            __syncthreads();
#pragma unroll
            for (int i = 0; i < 4; ++i) {
                int chunk = i * 256 + tid;
                int row = chunk >> 3;
                int kc = (chunk ^ (chunk >> 3)) & 7;
                gload_lds16(Ab + (long)row * 1280 + (k0 + kc * 8),
                            (char*)(&As[0][0]) + (i * 256 + wave * 64) * 16);
            }
#pragma unroll
            for (int i = 0; i < 4; ++i) {
                int chunk = i * 256 + tid;
                int row = chunk >> 3;
                int kc = (chunk ^ (chunk >> 3)) & 7;
                gload_lds16(Bb + (long)row * K + (k0 + kc * 8),
                            (char*)(&Bs[0][0]) + (i * 256 + wave * 64) * 16);
            }
            __syncthreads();
#pragma unroll
            for (int kk = 0; kk < 2; ++kk) {
                short8 af[4], bfr[4];
#pragma unroll
                for (int mi = 0; mi < 4; ++mi)
                    af[mi] = *(const short8*)&As[moff + mi * 16 + r16][((kk * 4 + g4) ^ r7) * 8];
#pragma unroll
                for (int ni = 0; ni < 4; ++ni)
                    bfr[ni] = *(const short8*)&Bs[noff + ni * 16 + r16][((kk * 4 + g4) ^ r7) * 8];
#pragma unroll
                for (int mi = 0; mi < 4; ++mi)
#pragma unroll
                    for (int ni = 0; ni < 4; ++ni)
                        acc[mi][ni] = __builtin_amdgcn_mfma_f32_16x16x32_bf16(
                            af[mi], bfr[ni], acc[mi][ni], 0, 0, 0);
            }
        }

        float s = 0.f, q = 0.f;
#pragma unroll
        for (int mi = 0; mi < 4; ++mi) {
#pragma unroll
            for (int ni = 0; ni < 4; ++ni) {
                int col = bx * 128 + noff + ni * 16 + r16;
                float bv = bias[col];
#pragma unroll
                for (int r = 0; r < 4; ++r) {
                    int row = by * 128 + moff + mi * 16 + g4 * 4 + r;
                    float v = acc[mi][ni][r] + bv;
                    Y[((long)bz * 1024 + row) * 640 + col] = __float2bfloat16(v);
                    s += v; q += v * v;
                }
            }
        }
        __syncthreads();
        float* red = (float*)&As[0][0];
        float* red2 = red + 256;
        red[tid] = s; red2[tid] = q;
        __syncthreads();
        for (int o = 128; o; o >>= 1) {
            if (tid < o) { red[tid] += red[tid + o]; red2[tid] += red2[tid + o]; }
            __syncthreads();
        }
        if (tid == 0) {
            atomicAdd(&stats[bz].x, red[0]);
            atomicAdd(&stats[bz].y, red2[0]);
        }
    } else {
        // ---------------- pool4: 4 query rows per block --------------------
        const int pw = blockIdx.x - 640;       // 0..4095
        const int b = pw >> 8;
        const int i0 = (pw & 255) * 4;
        float invq[4];
        int jloU = 1024, jhiU = -1;
#pragma unroll
        for (int q = 0; q < 4; ++q) {
            float sd = stdb[b * 1024 + i0 + q];
            float den = 1e-5f + 2.f * sd * sd;
            invq[q] = 1.f / den;
            int R = (int)sqrtf(11.5129255f * den) + 1;   // exp cutoff 1e-5
            int jl = max(0, i0 + q - R), jh = min(1023, i0 + q + R);
            jloU = min(jloU, jl); jhiU = max(jhiU, jh);
        }
        float a[4][3];
#pragma unroll
        for (int q = 0; q < 4; ++q) { a[q][0] = 0.f; a[q][1] = 0.f; a[q][2] = 0.f; }
        const float* fb = feats + (long)b * 1024 * 640;
        for (int j0 = jloU; j0 <= jhiU; j0 += 256) {
            int j = j0 + tid;
            float wj = (j <= jhiU) ? wb[b * 1024 + j] : 0.f;
            __syncthreads();
#pragma unroll
            for (int q = 0; q < 4; ++q) {
                float d = (float)(j - (i0 + q));
                cj4[q][tid] = __expf(-d * d * invq[q]) * wj;  // underflows to 0 beyond radius
            }
            __syncthreads();
            int lim = min(256, jhiU - j0 + 1);
            for (int t = 0; t < lim; ++t) {
                const float* fr = fb + (long)(j0 + t) * 640;
                float f0 = fr[tid];
                float f1 = fr[tid + 256];
                float f2 = (tid < 128) ? fr[tid + 512] : 0.f;
#pragma unroll
                for (int q = 0; q < 4; ++q) {
                    float cc = cj4[q][t];
                    a[q][0] += cc * f0; a[q][1] += cc * f1; a[q][2] += cc * f2;
                }
            }
        }
#pragma unroll
        for (int q = 0; q < 4; ++q) {
            long obase = ((long)b * 1024 + i0 + q) * 1280;
            long fbase = ((long)b * 1024 + i0 + q) * 640;
            acat[obase + tid] = __float2bfloat16(a[q][0] + feats[fbase + tid]);
            acat[obase + tid + 256] = __float2bfloat16(a[q][1] + feats[fbase + tid + 256]);
            if (tid < 128)
                acat[obase + tid + 512] = __float2bfloat16(a[q][2] + feats[fbase + tid + 512]);
        }
    }
}

// ---------------------------------------------------------------------------
// Mega-prep: sacc zero + feats pack (8-elem chunks) + all weight repacks.
// ---------------------------------------------------------------------------
__device__ __forceinline__ void repack1(const float* __restrict__ w,
                                        bf16* __restrict__ bt, long idx, int CI)
{
    int K3 = 3 * CI;
    int o = (int)(idx / K3);
    int k = (int)(idx % K3);
    int t = k / CI, ci = k % CI;
    bt[idx] = __float2bfloat16(w[(long)o * CI * 3 + ci * 3 + t]);
}

__global__ void prep_k(const float* __restrict__ feats,
                       const float* __restrict__ cp_w1, const float* __restrict__ cv_w1,
                       const float* __restrict__ cp_w2, const float* __restrict__ cv_w2,
                       const float* __restrict__ cp_w3, const float* __restrict__ cv_w3,
                       const float* __restrict__ mlp_w,
                       bf16* __restrict__ xp,
                       bf16* __restrict__ Bm1a, bf16* __restrict__ Bm1b,
                       bf16* __restrict__ Bcp2, bf16* __restrict__ Bcv2,
                       bf16* __restrict__ Bcp3, bf16* __restrict__ Bcv3,
                       bf16* __restrict__ Bmlp, float2* __restrict__ sacc)
{
    long idx = (long)blockIdx.x * 256 + threadIdx.x;
    if (idx < 80) { sacc[idx] = make_float2(0.f, 0.f); return; }
    idx -= 80;
    const long NPACK8 = 16L * 1026 * 640 / 8;
    if (idx < NPACK8) {
        long e = idx * 8;
        int c = (int)(e % 640);
        long t = e / 640;
        int r = (int)(t % 1026);
        int b = (int)(t / 1026);
        short8 o;
        if (r == 0 || r == 1025) {
#pragma unroll
            for (int j = 0; j < 8; ++j) o[j] = 0;
        } else {
            const float* src = feats + ((long)b * 1024 + (r - 1)) * 640 + c;
            f32x4 v0 = *(const f32x4*)src;
            f32x4 v1 = *(const f32x4*)(src + 4);
#pragma unroll
            for (int j = 0; j < 4; ++j) { o[j] = f2b(v0[j]); o[j + 4] = f2b(v1[j]); }
        }
        *(short8*)(xp + e) = o;
        return;
    }
    idx -= NPACK8;
    const long W1 = 1280L * 640 * 3;
    const long W2 = 1280L * 1280 * 3;
    if (idx < W1) { repack1(cp_w1, Bm1a, idx, 640); return; }
    idx -= W1;
    if (idx < W1) { repack1(cv_w1, Bm1b, idx, 640); return; }
    idx -= W1;
    if (idx < W2) { repack1(cp_w2, Bcp2, idx, 1280); return; }
    idx -= W2;
    if (idx < W2) { repack1(cv_w2, Bcv2, idx, 1280); return; }
    idx -= W2;
    if (idx < 2L * 1280 * 3) { repack1(cp_w3, Bcp3, idx, 1280); return; }
    idx -= 2L * 1280 * 3;
    const long W3 = 640L * 1280 * 3;
    if (idx < W3) { repack1(cv_w3, Bcv3, idx, 1280); return; }
    idx -= W3;
    if (idx < 640L * 1280) { Bmlp[idx] = __float2bfloat16(mlp_w[idx]); return; }
}

// ---------------------------------------------------------------------------
// Merged dual norm+pack with inline stat finalize.
// ---------------------------------------------------------------------------
__global__ void norm_pack2_k(const bf16* __restrict__ y0, const bf16* __restrict__ y1,
                             bf16* __restrict__ x0, bf16* __restrict__ x1,
                             const float2* __restrict__ sacc, int sbase, float invN)
{
    const int prob = blockIdx.y;
    const bf16* y = prob ? y1 : y0;
    bf16* xp = prob ? x1 : x0;
    long i8 = (long)blockIdx.x * 256 + threadIdx.x;
    const long total8 = 16L * 1026 * 1280 / 8;
    if (i8 >= total8) return;
    long e = i8 * 8;
    int c = (int)(e % 1280);
    long t = e / 1280;
    int r = (int)(t % 1026);
    int b = (int)(t / 1026);
    short8 o;
    if (r == 0 || r == 1025) {
#pragma unroll
        for (int j = 0; j < 8; ++j) o[j] = 0;
    } else {
        float2 a = sacc[sbase + prob * 16 + b];
        float m = a.x * invN;
        float rstd = rsqrtf(a.y * invN - m * m + EPS_LN);
        short8 v = *(const short8*)(y + ((long)b * 1024 + (r - 1)) * 1280 + c);
#pragma unroll
        for (int j = 0; j < 8; ++j)
            o[j] = f2b(leakyf((b2f(v[j]) - m) * rstd));
    }
    *(short8*)(xp + e) = o;
}

// cv3: Y bf16 -> leaky(LN) + feats -> Acat[:, :, 640:1280], inline stat.
__global__ void norm_addf_v_k(const bf16* __restrict__ y, const float2* __restrict__ sacc,
                              const float* __restrict__ feats, bf16* __restrict__ acat,
                              float invN)
{
    long i8 = (long)blockIdx.x * 256 + threadIdx.x;
    long total8 = 16L * 1024 * 640 / 8;
    if (i8 >= total8) return;
    long e = i8 * 8;
    int c = (int)(e % 640);
    int l = (int)((e / 640) % 1024);
    int b = (int)(e / (640L * 1024));
    float2 a = sacc[64 + b];
    float m = a.x * invN;
    float rstd = rsqrtf(a.y * invN - m * m + EPS_LN);
    short8 v = *(const short8*)(y + e);
    f32x4 f0 = *(const f32x4*)(feats + e);
    f32x4 f1 = *(const f32x4*)(feats + e + 4);
    short8 o;
#pragma unroll
    for (int j = 0; j < 4; ++j) {
        o[j] = f2b(leakyf((b2f(v[j]) - m) * rstd) + f0[j]);
        o[j + 4] = f2b(leakyf((b2f(v[j + 4]) - m) * rstd) + f1[j]);
    }
    *(short8*)(acat + ((long)b * 1024 + l) * 1280 + 640 + c) = o;
}

// ---------------------------------------------------------------------------
// cp conv3 (N=2): one wave per (b,l), short8-vectorized.
// ---------------------------------------------------------------------------
__global__ void conv3cp_k(const bf16* __restrict__ xp, const bf16* __restrict__ w3,
                          const float* __restrict__ b3, float* __restrict__ sw)
{
    int wid = (int)((blockIdx.x * 256 + threadIdx.x) >> 6);
    int lane = threadIdx.x & 63;
    int b = wid >> 10, l = wid & 1023;
    const short8* xr = (const short8*)(xp + ((long)b * 1026 + l) * 1280);
    const short8* w0 = (const short8*)w3;
    const short8* w1 = (const short8*)(w3 + 3840);
    float a0 = 0.f, a1 = 0.f;
    for (int c = lane; c < 480; c += 64) {
        short8 x = xr[c], u = w0[c], v = w1[c];
#pragma unroll
        for (int j = 0; j < 8; ++j) {
            float xf = b2f(x[j]);
            a0 += xf * b2f(u[j]);
            a1 += xf * b2f(v[j]);
        }
    }
    for (int o = 32; o; o >>= 1) { a0 += __shfl_down(a0, o); a1 += __shfl_down(a1, o); }
    if (lane == 0) {
        sw[b * 2048 + l] = a0 + b3[0];
        sw[b * 2048 + 1024 + l] = a1 + b3[1];
    }
}

// ---------------------------------------------------------------------------
__global__ __launch_bounds__(256) void cp_post_k(const float* __restrict__ sw,
                                                 float* __restrict__ stdb,
                                                 float* __restrict__ wb)
{
    int b = blockIdx.x, tid = threadIdx.x;
    __shared__ float s0[1024], s1[1024], red[256];
    const float* p = sw + b * 2048;
    float s = 0.f, q = 0.f;
    for (int l = tid; l < 1024; l += 256) {
        float v0 = p[l], v1 = p[1024 + l];
        s0[l] = v0; s1[l] = v1;
        s += v0 + v1; q += v0 * v0 + v1 * v1;
    }
    red[tid] = s; __syncthreads();
    for (int o = 128; o; o >>= 1) { if (tid < o) red[tid] += red[tid + o]; __syncthreads(); }
    float mean = red[0] / 2048.f; __syncthreads();
    red[tid] = q; __syncthreads();
    for (int o = 128; o; o >>= 1) { if (tid < o) red[tid] += red[tid + o]; __syncthreads(); }
    float inv = rsqrtf(red[0] / 2048.f - mean * mean + EPS_LN); __syncthreads();
    for (int l = tid; l < 1024; l += 256) {
        s0[l] = leakyf((s0[l] - mean) * inv);
        s1[l] = leakyf((s1[l] - mean) * inv);
    }
    __syncthreads();
    float mx = -1e30f;
    for (int l = tid; l < 1024; l += 256) mx = fmaxf(mx, s0[l]);
    red[tid] = mx; __syncthreads();
    for (int o = 128; o; o >>= 1) { if (tid < o) red[tid] = fmaxf(red[tid], red[tid + o]); __syncthreads(); }
    mx = red[0]; __syncthreads();
    float se = 0.f;
    for (int l = tid; l < 1024; l += 256) { float e = __expf(s0[l] - mx); s0[l] = e; se += e; }
    red[tid] = se; __syncthreads();
    for (int o = 128; o; o >>= 1) { if (tid < o) red[tid] += red[tid + o]; __syncthreads(); }
    float rs = 1.f / red[0]; __syncthreads();
    for (int l = tid; l < 1024; l += 256) stdb[b * 1024 + l] = 102.4f * s0[l] * rs;
    mx = -1e30f;
    for (int l = tid; l < 1024; l += 256) mx = fmaxf(mx, s1[l]);
    red[tid] = mx; __syncthreads();
    for (int o = 128; o; o >>= 1) { if (tid < o) red[tid] = fmaxf(red[tid], red[tid + o]); __syncthreads(); }
    mx = red[0]; __syncthreads();
    se = 0.f;
    for (int l = tid; l < 1024; l += 256) { float e = __expf(s1[l] - mx); s1[l] = e; se += e; }
    red[tid] = se; __syncthreads();
    for (int o = 128; o; o >>= 1) { if (tid < o) red[tid] += red[tid + o]; __syncthreads(); }
    rs = 1.f / red[0]; __syncthreads();
    for (int l = tid; l < 1024; l += 256) wb[b * 1024 + l] = s1[l] * rs;
}

// ---------------------------------------------------------------------------
extern "C" void kernel_launch(void* const* d_in, const int* in_sizes, int n_in,
                              void* d_out, int out_size, void* d_ws, size_t ws_size,
                              hipStream_t stream)
{
    const float* feats = (const float*)d_in[0];
    const float* cp_w1 = (const float*)d_in[1];
    const float* cp_b1 = (const float*)d_in[2];
    const float* cp_w2 = (const float*)d_in[3];
    const float* cp_b2 = (const float*)d_in[4];
    const float* cp_w3 = (const float*)d_in[5];
    const float* cp_b3 = (const float*)d_in[6];
    const float* cv_w1 = (const float*)d_in[7];
    const float* cv_b1 = (const float*)d_in[8];
    const float* cv_w2 = (const float*)d_in[9];
    const float* cv_b2 = (const float*)d_in[10];
    const float* cv_w3 = (const float*)d_in[11];
    const float* cv_b3 = (const float*)d_in[12];
    const float* mlp_w = (const float*)d_in[13];
    const float* mlp_b = (const float*)d_in[14];
    float* out = (float*)d_out;

    char* ws = (char*)d_ws;
    size_t off = 0;
    auto alloc = [&](size_t bytes) -> char* {
        char* p = ws + off;
        off += (bytes + 255) & ~(size_t)255;
        return p;
    };
    // R1 region: XpadF (21 MB, dead after r1 GEMM) overlaps Acat (42 MB,
    // written only by cv3_pool / norm_addf, both after r1).
    char* R1 = alloc(16L * 1024 * 1280 * 2);
    bf16* XpadF = (bf16*)R1;
    bf16* Acat = (bf16*)R1;
    bf16* Xp_cp = (bf16*)alloc(16L * 1026 * 1280 * 2);
    bf16* Xp_cv = (bf16*)alloc(16L * 1026 * 1280 * 2);
    bf16* Y0 = (bf16*)alloc(16L * 1024 * 1280 * 2);
    bf16* Y1 = (bf16*)alloc(16L * 1024 * 1280 * 2);
    bf16* Ycv3 = Y0;  // Y0 dead after r2 norm (cp)
    bf16* Bm1 = (bf16*)alloc(2560L * 1920 * 2);
    bf16* Bcp2 = (bf16*)alloc(1280L * 3840 * 2);
    bf16* Bcv2 = (bf16*)alloc(1280L * 3840 * 2);
    bf16* Bcp3 = (bf16*)alloc(2L * 3840 * 2);
    bf16* Bcv3 = (bf16*)alloc(640L * 3840 * 2);
    bf16* Bmlp = (bf16*)alloc(640L * 1280 * 2);
    float* swb = (float*)alloc(16L * 2048 * 4);
    float* stdb = (float*)alloc(16L * 1024 * 4);
    float* wbf = (float*)alloc(16L * 1024 * 4);
    float2* sacc = (float2*)alloc(80L * 8);
    (void)ws_size; (void)in_sizes; (void)n_in; (void)out_size;

    const long N28 = 16L * 1026 * 1280 / 8;
    const long NA8 = 16L * 1024 * 640 / 8;
    const long N1280 = 1024L * 1280, N640 = 1024L * 640;
    const float inv1280 = 1.f / (float)N1280, inv640 = 1.f / (float)N640;

    // ---- prep: sacc zero + feats pack + all weight repacks (1 launch) ----
    const long NPREP = 80 + 16L * 1026 * 640 / 8 + 2 * (1280L * 640 * 3)
                     + 2 * (1280L * 1280 * 3) + 2L * 1280 * 3
                     + 640L * 1280 * 3 + 640L * 1280;
    prep_k<<<(int)((NPREP + 255) / 256), 256, 0, stream>>>(
        feats, cp_w1, cv_w1, cp_w2, cv_w2, cp_w3, cv_w3, mlp_w,
        XpadF, Bm1, Bm1 + 1280L * 1920, Bcp2, Bcv2, Bcp3, Bcv3, Bmlp, sacc);

    // ---- round 1: cp1 + cv1 merged (2560 wg) ----
    gemm_dual<0><<<2560, 256, 0, stream>>>(
        XpadF, XpadF, 1026L * 640, 640, Bm1, Bm1 + 1280L * 1920,
        cp_b1, cv_b1, Y0, Y1, N1280, 1280, 1920, 10, 8, 1280,
        sacc, sacc + 16);
    norm_pack2_k<<<dim3((N28 + 255) / 256, 2), 256, 0, stream>>>(
        Y0, Y1, Xp_cp, Xp_cv, sacc, 0, inv1280);

    // ---- round 2: cp2 + cv2 merged ----
    gemm_dual<0><<<2560, 256, 0, stream>>>(
        Xp_cp, Xp_cv, 1026L * 1280, 1280, Bcp2, Bcv2,
        cp_b2, cv_b2, Y0, Y1, N1280, 1280, 3840, 10, 8, 1280,
        sacc + 32, sacc + 48);
    norm_pack2_k<<<dim3((N28 + 255) / 256, 2), 256, 0, stream>>>(
        Y0, Y1, Xp_cp, Xp_cv, sacc, 32, inv1280);

    // ---- cp tail prelude: conv3 -> softmaxes ----
    conv3cp_k<<<4096, 256, 0, stream>>>(Xp_cp, Bcp3, cp_b3, swb);
    cp_post_k<<<16, 256, 0, stream>>>(swb, stdb, wbf);

    // ---- fused: cv3 GEMM (640 blocks) + pooling (4096 blocks) ----
    cv3_pool_k<<<640 + 4096, 256, 0, stream>>>(
        Xp_cv, Bcv3, cv_b3, Ycv3, sacc + 64,
        feats, stdb, wbf, Acat);
    norm_addf_v_k<<<(NA8 + 255) / 256, 256, 0, stream>>>(Ycv3, sacc, feats, Acat, inv640);

    // ---- MLP ----
    gemm_dual<1><<<640, 256, 0, stream>>>(
        Acat, Acat, N1280, 1280, Bmlp, Bmlp,
        mlp_b, mlp_b, out, out, N640, 640, 1280, 5, 8, 640,
        nullptr, nullptr);
}

// Round 9
// 719.596 us; speedup vs baseline: 1.3114x; 1.0018x over previous
//
#include <hip/hip_runtime.h>
#include <hip/hip_bf16.h>
#include <math.h>

#define SLOPE 0.01f
#define EPS_LN 1e-5f

typedef __hip_bfloat16 bf16;
typedef __attribute__((ext_vector_type(8))) short short8;
typedef __attribute__((ext_vector_type(4))) float f32x4;

__device__ __forceinline__ float leakyf(float x) { return x < 0.f ? SLOPE * x : x; }

__device__ __forceinline__ float b2f(short s) {
    unsigned u = ((unsigned)(unsigned short)s) << 16;
    return __builtin_bit_cast(float, u);
}
__device__ __forceinline__ short f2b(float f) {
    __hip_bfloat16 h = __float2bfloat16(f);
    return *(short*)&h;
}

__device__ __forceinline__ void gload_lds16(const void* g, void* l) {
    __builtin_amdgcn_global_load_lds(
        (const __attribute__((address_space(1))) void*)g,
        (__attribute__((address_space(3))) void*)l, 16, 0, 0);
}

// ---------------------------------------------------------------------------
// 2-phase 128x128 GEMM (proven 985-1040 TF) with DUAL-problem branch.
// T2 swizzle (pre-swizzled global src + XOR ds_read), T1 XCD-chunked bids.
// Round-9: __launch_bounds__(256,4) -> 4 wg/CU (64 VGPR, 32 KiB LDS permit
// it); more resident waves hide the 2-phase barrier-drain stall (m114 model)
// and halve grid round-quantization.
// EPI 0: out bf16 + per-batch sum/sumsq atomics; EPI 1: f32 out, bias+leaky.
// ---------------------------------------------------------------------------
template <int EPI>
__global__ __launch_bounds__(256, 4) void gemm_dual(
    const bf16* __restrict__ A0, const bf16* __restrict__ A1, long sA, int ldA,
    const bf16* __restrict__ Bt0, const bf16* __restrict__ Bt1,
    const float* __restrict__ bias0, const float* __restrict__ bias1,
    void* __restrict__ Out0, void* __restrict__ Out1, long sO, int ldO, int K,
    int gx, int gy, int halfwg,
    float2* __restrict__ stats0, float2* __restrict__ stats1)
{
    __shared__ bf16 As[128][64];
    __shared__ bf16 Bs[128][64];

    const int nwg = gridDim.x;
    const int wid = (blockIdx.x & 7) * (nwg >> 3) + (blockIdx.x >> 3);
    const int branch = wid >= halfwg;
    const int w = wid - branch * halfwg;
    const int bx = w % gx;                 // bx-inner: A-panel L2-resident
    const int by = (w / gx) % gy;
    const int bz = w / (gx * gy);

    const bf16* A = branch ? A1 : A0;
    const bf16* Bt = branch ? Bt1 : Bt0;
    const float* bias = branch ? bias1 : bias0;
    void* Outv = branch ? Out1 : Out0;
    float2* stats = branch ? stats1 : stats0;

    const bf16* Ab = A + (long)bz * sA + (long)by * 128 * ldA;
    const bf16* Bb = Bt + (long)bx * 128 * K;
    const int tid = threadIdx.x;
    const int wave = tid >> 6, lane = tid & 63;
    const int moff = (wave >> 1) * 64, noff = (wave & 1) * 64;
    const int r16 = lane & 15, g4 = lane >> 4;
    const int r7 = r16 & 7;

    f32x4 acc[4][4];
#pragma unroll
    for (int i = 0; i < 4; ++i)
#pragma unroll
        for (int j = 0; j < 4; ++j)
            acc[i][j] = (f32x4){0.f, 0.f, 0.f, 0.f};

    for (int k0 = 0; k0 < K; k0 += 64) {
        __syncthreads();
#pragma unroll
        for (int i = 0; i < 4; ++i) {
            int chunk = i * 256 + tid;
            int row = chunk >> 3;
            int kc = (chunk ^ (chunk >> 3)) & 7;
            gload_lds16(Ab + (long)row * ldA + (k0 + kc * 8),
                        (char*)(&As[0][0]) + (i * 256 + wave * 64) * 16);
        }
#pragma unroll
        for (int i = 0; i < 4; ++i) {
            int chunk = i * 256 + tid;
            int row = chunk >> 3;
            int kc = (chunk ^ (chunk >> 3)) & 7;
            gload_lds16(Bb + (long)row * K + (k0 + kc * 8),
                        (char*)(&Bs[0][0]) + (i * 256 + wave * 64) * 16);
        }
        __syncthreads();
#pragma unroll
        for (int kk = 0; kk < 2; ++kk) {
            short8 af[4], bfr[4];
#pragma unroll
            for (int mi = 0; mi < 4; ++mi)
                af[mi] = *(const short8*)&As[moff + mi * 16 + r16][((kk * 4 + g4) ^ r7) * 8];
#pragma unroll
            for (int ni = 0; ni < 4; ++ni)
                bfr[ni] = *(const short8*)&Bs[noff + ni * 16 + r16][((kk * 4 + g4) ^ r7) * 8];
#pragma unroll
            for (int mi = 0; mi < 4; ++mi)
#pragma unroll
                for (int ni = 0; ni < 4; ++ni)
                    acc[mi][ni] = __builtin_amdgcn_mfma_f32_16x16x32_bf16(
                        af[mi], bfr[ni], acc[mi][ni], 0, 0, 0);
        }
    }

    float s = 0.f, q = 0.f;
#pragma unroll
    for (int mi = 0; mi < 4; ++mi) {
#pragma unroll
        for (int ni = 0; ni < 4; ++ni) {
            int col = bx * 128 + noff + ni * 16 + r16;
            float bv = bias[col];
#pragma unroll
            for (int r = 0; r < 4; ++r) {
                int row = by * 128 + moff + mi * 16 + g4 * 4 + r;
                float v = acc[mi][ni][r] + bv;
                if (EPI == 1) {
                    ((float*)Outv)[(long)bz * sO + (long)row * ldO + col] = leakyf(v);
                } else {
                    ((bf16*)Outv)[(long)bz * sO + (long)row * ldO + col] = __float2bfloat16(v);
                    s += v; q += v * v;
                }
            }
        }
    }
    if (EPI == 0) {
        __syncthreads();
        float* red = (float*)&As[0][0];
        float* red2 = red + 256;
        red[tid] = s; red2[tid] = q;
        __syncthreads();
        for (int o = 128; o; o >>= 1) {
            if (tid < o) { red[tid] += red[tid + o]; red2[tid] += red2[tid + o]; }
            __syncthreads();
        }
        if (tid == 0) {
            atomicAdd(&stats[bz].x, red[0]);
            atomicAdd(&stats[bz].y, red2[0]);
        }
    }
}

// ---------------------------------------------------------------------------
// Fused cv3-GEMM + pooling (round-8 proven). Round-9: 4 wg/CU (36.9 KiB LDS
// x4 = 147 KiB <= 160 KiB).
// ---------------------------------------------------------------------------
__global__ __launch_bounds__(256, 4) void cv3_pool_k(
    const bf16* __restrict__ Axp, const bf16* __restrict__ Bt,
    const float* __restrict__ bias, bf16* __restrict__ Y,
    float2* __restrict__ stats,
    const float* __restrict__ feats, const float* __restrict__ stdb,
    const float* __restrict__ wb, bf16* __restrict__ acat)
{
    __shared__ bf16 As[128][64];
    __shared__ bf16 Bs[128][64];
    __shared__ float cj4[4][256];

    const int tid = threadIdx.x;
    if (blockIdx.x < 640) {
        // ---------------- cv3 GEMM (K=3840, gx=5, gy=8, 16 batches) --------
        const int wid = (blockIdx.x & 7) * 80 + (blockIdx.x >> 3);
        const int bx = wid % 5;
        const int by = (wid / 5) % 8;
        const int bz = wid / 40;
        const int K = 3840;
        const bf16* Ab = Axp + ((long)bz * 1026 + (long)by * 128) * 1280;
        const bf16* Bb = Bt + (long)bx * 128 * K;
        const int wave = tid >> 6, lane = tid & 63;
        const int moff = (wave >> 1) * 64, noff = (wave & 1) * 64;
        const int r16 = lane & 15, g4 = lane >> 4;
        const int r7 = r16 & 7;

        f32x4 acc[4][4];
#pragma unroll
        for (int i = 0; i < 4; ++i)
#pragma unroll
            for (int j = 0; j < 4; ++j)
                acc[i][j] = (f32x4){0.f, 0.f, 0.f, 0.f};

        for (int k0 = 0; k0 < K; k0 += 64) {
            __syncthreads();
#pragma unroll
            for (int i = 0; i < 4; ++i) {
                int chunk = i * 256 + tid;
                int row = chunk >> 3;
                int kc = (chunk ^ (chunk >> 3)) & 7;
                gload_lds16(Ab + (long)row * 1280 + (k0 + kc * 8),
                            (char*)(&As[0][0]) + (i * 256 + wave * 64) * 16);
            }
#pragma unroll
            for (int i = 0; i < 4; ++i) {
                int chunk = i * 256 + tid;
                int row = chunk >> 3;
                int kc = (chunk ^ (chunk >> 3)) & 7;
                gload_lds16(Bb + (long)row * K + (k0 + kc * 8),
                            (char*)(&Bs[0][0]) + (i * 256 + wave * 64) * 16);
            }
            __syncthreads();
#pragma unroll
            for (int kk = 0; kk < 2; ++kk) {
                short8 af[4], bfr[4];
#pragma unroll
                for (int mi = 0; mi < 4; ++mi)
                    af[mi] = *(const short8*)&As[moff + mi * 16 + r16][((kk * 4 + g4) ^ r7) * 8];
#pragma unroll
                for (int ni = 0; ni < 4; ++ni)
                    bfr[ni] = *(const short8*)&Bs[noff + ni * 16 + r16][((kk * 4 + g4) ^ r7) * 8];
#pragma unroll
                for (int mi = 0; mi < 4; ++mi)
#pragma unroll
                    for (int ni = 0; ni < 4; ++ni)
                        acc[mi][ni] = __builtin_amdgcn_mfma_f32_16x16x32_bf16(
                            af[mi], bfr[ni], acc[mi][ni], 0, 0, 0);
            }
        }

        float s = 0.f, q = 0.f;
#pragma unroll
        for (int mi = 0; mi < 4; ++mi) {
#pragma unroll
            for (int ni = 0; ni < 4; ++ni) {
                int col = bx * 128 + noff + ni * 16 + r16;
                float bv = bias[col];
#pragma unroll
                for (int r = 0; r < 4; ++r) {
                    int row = by * 128 + moff + mi * 16 + g4 * 4 + r;
                    float v = acc[mi][ni][r] + bv;
                    Y[((long)bz * 1024 + row) * 640 + col] = __float2bfloat16(v);
                    s += v; q += v * v;
                }
            }
        }
        __syncthreads();
        float* red = (float*)&As[0][0];
        float* red2 = red + 256;
        red[tid] = s; red2[tid] = q;
        __syncthreads();
        for (int o = 128; o; o >>= 1) {
            if (tid < o) { red[tid] += red[tid + o]; red2[tid] += red2[tid + o]; }
            __syncthreads();
        }
        if (tid == 0) {
            atomicAdd(&stats[bz].x, red[0]);
            atomicAdd(&stats[bz].y, red2[0]);
        }
    } else {
        // ---------------- pool4: 4 query rows per block --------------------
        const int pw = blockIdx.x - 640;       // 0..4095
        const int b = pw >> 8;
        const int i0 = (pw & 255) * 4;
        float invq[4];
        int jloU = 1024, jhiU = -1;
#pragma unroll
        for (int q = 0; q < 4; ++q) {
            float sd = stdb[b * 1024 + i0 + q];
            float den = 1e-5f + 2.f * sd * sd;
            invq[q] = 1.f / den;
            int R = (int)sqrtf(11.5129255f * den) + 1;   // exp cutoff 1e-5
            int jl = max(0, i0 + q - R), jh = min(1023, i0 + q + R);
            jloU = min(jloU, jl); jhiU = max(jhiU, jh);
        }
        float a[4][3];
#pragma unroll
        for (int q = 0; q < 4; ++q) { a[q][0] = 0.f; a[q][1] = 0.f; a[q][2] = 0.f; }
        const float* fb = feats + (long)b * 1024 * 640;
        for (int j0 = jloU; j0 <= jhiU; j0 += 256) {
            int j = j0 + tid;
            float wj = (j <= jhiU) ? wb[b * 1024 + j] : 0.f;
            __syncthreads();
#pragma unroll
            for (int q = 0; q < 4; ++q) {
                float d = (float)(j - (i0 + q));
                cj4[q][tid] = __expf(-d * d * invq[q]) * wj;  // underflows to 0 beyond radius
            }
            __syncthreads();
            int lim = min(256, jhiU - j0 + 1);
            for (int t = 0; t < lim; ++t) {
                const float* fr = fb + (long)(j0 + t) * 640;
                float f0 = fr[tid];
                float f1 = fr[tid + 256];
                float f2 = (tid < 128) ? fr[tid + 512] : 0.f;
#pragma unroll
                for (int q = 0; q < 4; ++q) {
                    float cc = cj4[q][t];
                    a[q][0] += cc * f0; a[q][1] += cc * f1; a[q][2] += cc * f2;
                }
            }
        }
#pragma unroll
        for (int q = 0; q < 4; ++q) {
            long obase = ((long)b * 1024 + i0 + q) * 1280;
            long fbase = ((long)b * 1024 + i0 + q) * 640;
            acat[obase + tid] = __float2bfloat16(a[q][0] + feats[fbase + tid]);
            acat[obase + tid + 256] = __float2bfloat16(a[q][1] + feats[fbase + tid + 256]);
            if (tid < 128)
                acat[obase + tid + 512] = __float2bfloat16(a[q][2] + feats[fbase + tid + 512]);
        }
    }
}

// ---------------------------------------------------------------------------
// Mega-prep: sacc zero + feats pack (8-elem chunks) + all weight repacks.
// ---------------------------------------------------------------------------
__device__ __forceinline__ void repack1(const float* __restrict__ w,
                                        bf16* __restrict__ bt, long idx, int CI)
{
    int K3 = 3 * CI;
    int o = (int)(idx / K3);
    int k = (int)(idx % K3);
    int t = k / CI, ci = k % CI;
    bt[idx] = __float2bfloat16(w[(long)o * CI * 3 + ci * 3 + t]);
}

__global__ void prep_k(const float* __restrict__ feats,
                       const float* __restrict__ cp_w1, const float* __restrict__ cv_w1,
                       const float* __restrict__ cp_w2, const float* __restrict__ cv_w2,
                       const float* __restrict__ cp_w3, const float* __restrict__ cv_w3,
                       const float* __restrict__ mlp_w,
                       bf16* __restrict__ xp,
                       bf16* __restrict__ Bm1a, bf16* __restrict__ Bm1b,
                       bf16* __restrict__ Bcp2, bf16* __restrict__ Bcv2,
                       bf16* __restrict__ Bcp3, bf16* __restrict__ Bcv3,
                       bf16* __restrict__ Bmlp, float2* __restrict__ sacc)
{
    long idx = (long)blockIdx.x * 256 + threadIdx.x;
    if (idx < 80) { sacc[idx] = make_float2(0.f, 0.f); return; }
    idx -= 80;
    const long NPACK8 = 16L * 1026 * 640 / 8;
    if (idx < NPACK8) {
        long e = idx * 8;
        int c = (int)(e % 640);
        long t = e / 640;
        int r = (int)(t % 1026);
        int b = (int)(t / 1026);
        short8 o;
        if (r == 0 || r == 1025) {
#pragma unroll
            for (int j = 0; j < 8; ++j) o[j] = 0;
        } else {
            const float* src = feats + ((long)b * 1024 + (r - 1)) * 640 + c;
            f32x4 v0 = *(const f32x4*)src;
            f32x4 v1 = *(const f32x4*)(src + 4);
#pragma unroll
            for (int j = 0; j < 4; ++j) { o[j] = f2b(v0[j]); o[j + 4] = f2b(v1[j]); }
        }
        *(short8*)(xp + e) = o;
        return;
    }
    idx -= NPACK8;
    const long W1 = 1280L * 640 * 3;
    const long W2 = 1280L * 1280 * 3;
    if (idx < W1) { repack1(cp_w1, Bm1a, idx, 640); return; }
    idx -= W1;
    if (idx < W1) { repack1(cv_w1, Bm1b, idx, 640); return; }
    idx -= W1;
    if (idx < W2) { repack1(cp_w2, Bcp2, idx, 1280); return; }
    idx -= W2;
    if (idx < W2) { repack1(cv_w2, Bcv2, idx, 1280); return; }
    idx -= W2;
    if (idx < 2L * 1280 * 3) { repack1(cp_w3, Bcp3, idx, 1280); return; }
    idx -= 2L * 1280 * 3;
    const long W3 = 640L * 1280 * 3;
    if (idx < W3) { repack1(cv_w3, Bcv3, idx, 1280); return; }
    idx -= W3;
    if (idx < 640L * 1280) { Bmlp[idx] = __float2bfloat16(mlp_w[idx]); return; }
}

// ---------------------------------------------------------------------------
// Merged dual norm+pack with inline stat finalize.
// ---------------------------------------------------------------------------
__global__ void norm_pack2_k(const bf16* __restrict__ y0, const bf16* __restrict__ y1,
                             bf16* __restrict__ x0, bf16* __restrict__ x1,
                             const float2* __restrict__ sacc, int sbase, float invN)
{
    const int prob = blockIdx.y;
    const bf16* y = prob ? y1 : y0;
    bf16* xp = prob ? x1 : x0;
    long i8 = (long)blockIdx.x * 256 + threadIdx.x;
    const long total8 = 16L * 1026 * 1280 / 8;
    if (i8 >= total8) return;
    long e = i8 * 8;
    int c = (int)(e % 1280);
    long t = e / 1280;
    int r = (int)(t % 1026);
    int b = (int)(t / 1026);
    short8 o;
    if (r == 0 || r == 1025) {
#pragma unroll
        for (int j = 0; j < 8; ++j) o[j] = 0;
    } else {
        float2 a = sacc[sbase + prob * 16 + b];
        float m = a.x * invN;
        float rstd = rsqrtf(a.y * invN - m * m + EPS_LN);
        short8 v = *(const short8*)(y + ((long)b * 1024 + (r - 1)) * 1280 + c);
#pragma unroll
        for (int j = 0; j < 8; ++j)
            o[j] = f2b(leakyf((b2f(v[j]) - m) * rstd));
    }
    *(short8*)(xp + e) = o;
}

// cv3: Y bf16 -> leaky(LN) + feats -> Acat[:, :, 640:1280], inline stat.
__global__ void norm_addf_v_k(const bf16* __restrict__ y, const float2* __restrict__ sacc,
                              const float* __restrict__ feats, bf16* __restrict__ acat,
                              float invN)
{
    long i8 = (long)blockIdx.x * 256 + threadIdx.x;
    long total8 = 16L * 1024 * 640 / 8;
    if (i8 >= total8) return;
    long e = i8 * 8;
    int c = (int)(e % 640);
    int l = (int)((e / 640) % 1024);
    int b = (int)(e / (640L * 1024));
    float2 a = sacc[64 + b];
    float m = a.x * invN;
    float rstd = rsqrtf(a.y * invN - m * m + EPS_LN);
    short8 v = *(const short8*)(y + e);
    f32x4 f0 = *(const f32x4*)(feats + e);
    f32x4 f1 = *(const f32x4*)(feats + e + 4);
    short8 o;
#pragma unroll
    for (int j = 0; j < 4; ++j) {
        o[j] = f2b(leakyf((b2f(v[j]) - m) * rstd) + f0[j]);
        o[j + 4] = f2b(leakyf((b2f(v[j + 4]) - m) * rstd) + f1[j]);
    }
    *(short8*)(acat + ((long)b * 1024 + l) * 1280 + 640 + c) = o;
}

// ---------------------------------------------------------------------------
// cp conv3 (N=2): one wave per (b,l), short8-vectorized.
// ---------------------------------------------------------------------------
__global__ void conv3cp_k(const bf16* __restrict__ xp, const bf16* __restrict__ w3,
                          const float* __restrict__ b3, float* __restrict__ sw)
{
    int wid = (int)((blockIdx.x * 256 + threadIdx.x) >> 6);
    int lane = threadIdx.x & 63;
    int b = wid >> 10, l = wid & 1023;
    const short8* xr = (const short8*)(xp + ((long)b * 1026 + l) * 1280);
    const short8* w0 = (const short8*)w3;
    const short8* w1 = (const short8*)(w3 + 3840);
    float a0 = 0.f, a1 = 0.f;
    for (int c = lane; c < 480; c += 64) {
        short8 x = xr[c], u = w0[c], v = w1[c];
#pragma unroll
        for (int j = 0; j < 8; ++j) {
            float xf = b2f(x[j]);
            a0 += xf * b2f(u[j]);
            a1 += xf * b2f(v[j]);
        }
    }
    for (int o = 32; o; o >>= 1) { a0 += __shfl_down(a0, o); a1 += __shfl_down(a1, o); }
    if (lane == 0) {
        sw[b * 2048 + l] = a0 + b3[0];
        sw[b * 2048 + 1024 + l] = a1 + b3[1];
    }
}

// ---------------------------------------------------------------------------
__global__ __launch_bounds__(256) void cp_post_k(const float* __restrict__ sw,
                                                 float* __restrict__ stdb,
                                                 float* __restrict__ wb)
{
    int b = blockIdx.x, tid = threadIdx.x;
    __shared__ float s0[1024], s1[1024], red[256];
    const float* p = sw + b * 2048;
    float s = 0.f, q = 0.f;
    for (int l = tid; l < 1024; l += 256) {
        float v0 = p[l], v1 = p[1024 + l];
        s0[l] = v0; s1[l] = v1;
        s += v0 + v1; q += v0 * v0 + v1 * v1;
    }
    red[tid] = s; __syncthreads();
    for (int o = 128; o; o >>= 1) { if (tid < o) red[tid] += red[tid + o]; __syncthreads(); }
    float mean = red[0] / 2048.f; __syncthreads();
    red[tid] = q; __syncthreads();
    for (int o = 128; o; o >>= 1) { if (tid < o) red[tid] += red[tid + o]; __syncthreads(); }
    float inv = rsqrtf(red[0] / 2048.f - mean * mean + EPS_LN); __syncthreads();
    for (int l = tid; l < 1024; l += 256) {
        s0[l] = leakyf((s0[l] - mean) * inv);
        s1[l] = leakyf((s1[l] - mean) * inv);
    }
    __syncthreads();
    float mx = -1e30f;
    for (int l = tid; l < 1024; l += 256) mx = fmaxf(mx, s0[l]);
    red[tid] = mx; __syncthreads();
    for (int o = 128; o; o >>= 1) { if (tid < o) red[tid] = fmaxf(red[tid], red[tid + o]); __syncthreads(); }
    mx = red[0]; __syncthreads();
    float se = 0.f;
    for (int l = tid; l < 1024; l += 256) { float e = __expf(s0[l] - mx); s0[l] = e; se += e; }
    red[tid] = se; __syncthreads();
    for (int o = 128; o; o >>= 1) { if (tid < o) red[tid] += red[tid + o]; __syncthreads(); }
    float rs = 1.f / red[0]; __syncthreads();
    for (int l = tid; l < 1024; l += 256) stdb[b * 1024 + l] = 102.4f * s0[l] * rs;
    mx = -1e30f;
    for (int l = tid; l < 1024; l += 256) mx = fmaxf(mx, s1[l]);
    red[tid] = mx; __syncthreads();
    for (int o = 128; o; o >>= 1) { if (tid < o) red[tid] = fmaxf(red[tid], red[tid + o]); __syncthreads(); }
    mx = red[0]; __syncthreads();
    se = 0.f;
    for (int l = tid; l < 1024; l += 256) { float e = __expf(s1[l] - mx); s1[l] = e; se += e; }
    red[tid] = se; __syncthreads();
    for (int o = 128; o; o >>= 1) { if (tid < o) red[tid] += red[tid + o]; __syncthreads(); }
    rs = 1.f / red[0]; __syncthreads();
    for (int l = tid; l < 1024; l += 256) wb[b * 1024 + l] = s1[l] * rs;
}

// ---------------------------------------------------------------------------
extern "C" void kernel_launch(void* const* d_in, const int* in_sizes, int n_in,
                              void* d_out, int out_size, void* d_ws, size_t ws_size,
                              hipStream_t stream)
{
    const float* feats = (const float*)d_in[0];
    const float* cp_w1 = (const float*)d_in[1];
    const float* cp_b1 = (const float*)d_in[2];
    const float* cp_w2 = (const float*)d_in[3];
    const float* cp_b2 = (const float*)d_in[4];
    const float* cp_w3 = (const float*)d_in[5];
    const float* cp_b3 = (const float*)d_in[6];
    const float* cv_w1 = (const float*)d_in[7];
    const float* cv_b1 = (const float*)d_in[8];
    const float* cv_w2 = (const float*)d_in[9];
    const float* cv_b2 = (const float*)d_in[10];
    const float* cv_w3 = (const float*)d_in[11];
    const float* cv_b3 = (const float*)d_in[12];
    const float* mlp_w = (const float*)d_in[13];
    const float* mlp_b = (const float*)d_in[14];
    float* out = (float*)d_out;

    char* ws = (char*)d_ws;
    size_t off = 0;
    auto alloc = [&](size_t bytes) -> char* {
        char* p = ws + off;
        off += (bytes + 255) & ~(size_t)255;
        return p;
    };
    // R1 region: XpadF (21 MB, dead after r1 GEMM) overlaps Acat (42 MB,
    // written only by cv3_pool / norm_addf, both after r1).
    char* R1 = alloc(16L * 1024 * 1280 * 2);
    bf16* XpadF = (bf16*)R1;
    bf16* Acat = (bf16*)R1;
    bf16* Xp_cp = (bf16*)alloc(16L * 1026 * 1280 * 2);
    bf16* Xp_cv = (bf16*)alloc(16L * 1026 * 1280 * 2);
    bf16* Y0 = (bf16*)alloc(16L * 1024 * 1280 * 2);
    bf16* Y1 = (bf16*)alloc(16L * 1024 * 1280 * 2);
    bf16* Ycv3 = Y0;  // Y0 dead after r2 norm (cp)
    bf16* Bm1 = (bf16*)alloc(2560L * 1920 * 2);
    bf16* Bcp2 = (bf16*)alloc(1280L * 3840 * 2);
    bf16* Bcv2 = (bf16*)alloc(1280L * 3840 * 2);
    bf16* Bcp3 = (bf16*)alloc(2L * 3840 * 2);
    bf16* Bcv3 = (bf16*)alloc(640L * 3840 * 2);
    bf16* Bmlp = (bf16*)alloc(640L * 1280 * 2);
    float* swb = (float*)alloc(16L * 2048 * 4);
    float* stdb = (float*)alloc(16L * 1024 * 4);
    float* wbf = (float*)alloc(16L * 1024 * 4);
    float2* sacc = (float2*)alloc(80L * 8);
    (void)ws_size; (void)in_sizes; (void)n_in; (void)out_size;

    const long N28 = 16L * 1026 * 1280 / 8;
    const long NA8 = 16L * 1024 * 640 / 8;
    const long N1280 = 1024L * 1280, N640 = 1024L * 640;
    const float inv1280 = 1.f / (float)N1280, inv640 = 1.f / (float)N640;

    // ---- prep: sacc zero + feats pack + all weight repacks (1 launch) ----
    const long NPREP = 80 + 16L * 1026 * 640 / 8 + 2 * (1280L * 640 * 3)
                     + 2 * (1280L * 1280 * 3) + 2L * 1280 * 3
                     + 640L * 1280 * 3 + 640L * 1280;
    prep_k<<<(int)((NPREP + 255) / 256), 256, 0, stream>>>(
        feats, cp_w1, cv_w1, cp_w2, cv_w2, cp_w3, cv_w3, mlp_w,
        XpadF, Bm1, Bm1 + 1280L * 1920, Bcp2, Bcv2, Bcp3, Bcv3, Bmlp, sacc);

    // ---- round 1: cp1 + cv1 merged (2560 wg) ----
    gemm_dual<0><<<2560, 256, 0, stream>>>(
        XpadF, XpadF, 1026L * 640, 640, Bm1, Bm1 + 1280L * 1920,
        cp_b1, cv_b1, Y0, Y1, N1280, 1280, 1920, 10, 8, 1280,
        sacc, sacc + 16);
    norm_pack2_k<<<dim3((N28 + 255) / 256, 2), 256, 0, stream>>>(
        Y0, Y1, Xp_cp, Xp_cv, sacc, 0, inv1280);

    // ---- round 2: cp2 + cv2 merged ----
    gemm_dual<0><<<2560, 256, 0, stream>>>(
        Xp_cp, Xp_cv, 1026L * 1280, 1280, Bcp2, Bcv2,
        cp_b2, cv_b2, Y0, Y1, N1280, 1280, 3840, 10, 8, 1280,
        sacc + 32, sacc + 48);
    norm_pack2_k<<<dim3((N28 + 255) / 256, 2), 256, 0, stream>>>(
        Y0, Y1, Xp_cp, Xp_cv, sacc, 32, inv1280);

    // ---- cp tail prelude: conv3 -> softmaxes ----
    conv3cp_k<<<4096, 256, 0, stream>>>(Xp_cp, Bcp3, cp_b3, swb);
    cp_post_k<<<16, 256, 0, stream>>>(swb, stdb, wbf);

    // ---- fused: cv3 GEMM (640 blocks) + pooling (4096 blocks) ----
    cv3_pool_k<<<640 + 4096, 256, 0, stream>>>(
        Xp_cv, Bcv3, cv_b3, Ycv3, sacc + 64,
        feats, stdb, wbf, Acat);
    norm_addf_v_k<<<(NA8 + 255) / 256, 256, 0, stream>>>(Ycv3, sacc, feats, Acat, inv640);

    // ---- MLP ----
    gemm_dual<1><<<640, 256, 0, stream>>>(
        Acat, Acat, N1280, 1280, Bmlp, Bmlp,
        mlp_b, mlp_b, out, out, N640, 640, 1280, 5, 8, 640,
        nullptr, nullptr);
}